// Round 2
// baseline (2701.089 us; speedup 1.0000x reference)
//
#include <hip/hip_runtime.h>
#include <math.h>

typedef unsigned short u16;
typedef unsigned int u32;

constexpr float EPS_BN = 1e-5f;
constexpr float NEG = 0.1f;

static inline int cdiv(int a, int b) { return (a + b - 1) / b; }

// ---------------- bf16 helpers ----------------

__device__ __forceinline__ float b2f_lo(u32 v) { return __uint_as_float(v << 16); }
__device__ __forceinline__ float b2f_hi(u32 v) { return __uint_as_float(v & 0xFFFF0000u); }
__device__ __forceinline__ float b2f(u16 v) { return __uint_as_float(((u32)v) << 16); }
__device__ __forceinline__ u16 f2b(float f) {
  u32 u = __float_as_uint(f);
  u32 r = u + 0x7FFFu + ((u >> 16) & 1u);
  return (u16)(r >> 16);
}
__device__ __forceinline__ u32 pack2(float a, float b) {
  return (u32)f2b(a) | ((u32)f2b(b) << 16);
}
__device__ __forceinline__ void unpack8(uint4 v, float* o) {
  o[0] = b2f_lo(v.x); o[1] = b2f_hi(v.x);
  o[2] = b2f_lo(v.y); o[3] = b2f_hi(v.y);
  o[4] = b2f_lo(v.z); o[5] = b2f_hi(v.z);
  o[6] = b2f_lo(v.w); o[7] = b2f_hi(v.w);
}

// ---------------- CSR build ----------------

__global__ void k_zero_i32(int* p, int n) {
  int i = blockIdx.x * blockDim.x + threadIdx.x;
  if (i < n) p[i] = 0;
}

__global__ void k_hist(const int* __restrict__ dst, int* __restrict__ deg, int n) {
  int i = blockIdx.x * blockDim.x + threadIdx.x;
  if (i < n) atomicAdd(&deg[dst[i]], 1);
}

// single-block exclusive scan: rowoff[0..n]
__global__ void k_scan(const int* __restrict__ deg, int* __restrict__ rowoff, int n) {
  __shared__ int s[1024];
  __shared__ int carry;
  int tid = threadIdx.x;
  if (tid == 0) { carry = 0; rowoff[0] = 0; }
  __syncthreads();
  for (int base = 0; base < n; base += 4096) {
    int idx = base + tid * 4;
    int v0 = (idx     < n) ? deg[idx]     : 0;
    int v1 = (idx + 1 < n) ? deg[idx + 1] : 0;
    int v2 = (idx + 2 < n) ? deg[idx + 2] : 0;
    int v3 = (idx + 3 < n) ? deg[idx + 3] : 0;
    int ts = v0 + v1 + v2 + v3;
    s[tid] = ts;
    __syncthreads();
    for (int off = 1; off < 1024; off <<= 1) {
      int t = (tid >= off) ? s[tid - off] : 0;
      __syncthreads();
      s[tid] += t;
      __syncthreads();
    }
    int excl = s[tid] - ts;
    int c = carry;
    int p0 = c + excl + v0;
    int p1 = p0 + v1, p2 = p1 + v2, p3 = p2 + v3;
    if (idx + 1 <= n) rowoff[idx + 1] = p0;
    if (idx + 2 <= n) rowoff[idx + 2] = p1;
    if (idx + 3 <= n) rowoff[idx + 3] = p2;
    if (idx + 4 <= n) rowoff[idx + 4] = p3;
    __syncthreads();
    if (tid == 1023) carry = c + s[1023];
    __syncthreads();
  }
}

__global__ void k_fill(const int* __restrict__ src, const int* __restrict__ dst,
                       const int* __restrict__ rowoff, int* __restrict__ cursor,
                       int* __restrict__ col, int n) {
  int i = blockIdx.x * blockDim.x + threadIdx.x;
  if (i < n) {
    int d = dst[i];
    int p = atomicAdd(&cursor[d], 1);
    col[rowoff[d] + p] = src[i];
  }
}

__global__ void k_dis(const int* __restrict__ deg, float* __restrict__ dis, int n) {
  int i = blockIdx.x * blockDim.x + threadIdx.x;
  if (i < n) dis[i] = rsqrtf((float)deg[i] + 1.0f);
}

// ---------------- L1 pieces (dim 3 padded to 4, bf16) ----------------

__global__ void k_u1(const float* __restrict__ x, const float* __restrict__ dis,
                     u16* __restrict__ u, int n) {
  int i = blockIdx.x * blockDim.x + threadIdx.x;
  if (i >= n) return;
  float d = dis[i];
  u32 p0 = pack2(d * x[i * 3 + 0], d * x[i * 3 + 1]);
  u32 p1 = pack2(d * x[i * 3 + 2], 0.0f);
  ((uint2*)u)[i] = make_uint2(p0, p1);
}

__global__ void k_agg1(const u16* __restrict__ u, const int* __restrict__ rowoff,
                       const int* __restrict__ col, const float* __restrict__ dis,
                       u16* __restrict__ a, int n) {
  int i = blockIdx.x * blockDim.x + threadIdx.x;
  if (i >= n) return;
  const uint2* u2 = (const uint2*)u;
  uint2 v = u2[i];
  float a0 = b2f_lo(v.x), a1 = b2f_hi(v.x), a2 = b2f_lo(v.y);
  int beg = rowoff[i], end = rowoff[i + 1];
  for (int e = beg; e < end; ++e) {
    uint2 w = u2[col[e]];
    a0 += b2f_lo(w.x); a1 += b2f_hi(w.x); a2 += b2f_lo(w.y);
  }
  float d = dis[i];
  ((uint2*)a)[i] = make_uint2(pack2(d * a0, d * a1), pack2(d * a2, 0.0f));
}

__global__ void k_gemm1(const u16* __restrict__ a, const float* __restrict__ W,
                        const float* __restrict__ b, u16* __restrict__ z, int n) {
  __shared__ float Ws[3][64];
  __shared__ float bs[64];
  int tid = threadIdx.x;
  if (tid < 192) Ws[tid / 64][tid % 64] = W[tid];
  if (tid < 64) bs[tid] = b[tid];
  __syncthreads();
  int f = tid % 64, r = tid / 64;
  int node = blockIdx.x * 4 + r;
  if (node >= n) return;
  uint2 v = ((const uint2*)a)[node];
  float a0 = b2f_lo(v.x), a1 = b2f_hi(v.x), a2 = b2f_lo(v.y);
  float zv = a0 * Ws[0][f] + a1 * Ws[1][f] + a2 * Ws[2][f] + bs[f];
  z[(size_t)node * 64 + f] = f2b(zv);
}

// ---------------- generic layer pieces ----------------

// in-place: z -> u = dis * lrelu(z*scale + shift); D = 8<<lg bf16/row
__global__ void k_u(u16* __restrict__ z, const float* __restrict__ scaleF,
                    const float* __restrict__ shiftF, const float* __restrict__ dis,
                    int n, int lg) {
  size_t idx = (size_t)blockIdx.x * blockDim.x + threadIdx.x;
  size_t tot = ((size_t)n) << lg;
  if (idx >= tot) return;
  int g = (int)(idx & ((1u << lg) - 1));
  int node = (int)(idx >> lg);
  uint4 v = ((const uint4*)z)[idx];
  float f[8];
  unpack8(v, f);
  int f0 = g * 8;
  float4 s0 = *(const float4*)&scaleF[f0];
  float4 s1 = *(const float4*)&scaleF[f0 + 4];
  float4 h0 = *(const float4*)&shiftF[f0];
  float4 h1 = *(const float4*)&shiftF[f0 + 4];
  float d = dis[node];
  float o[8];
  o[0] = f[0] * s0.x + h0.x; o[1] = f[1] * s0.y + h0.y;
  o[2] = f[2] * s0.z + h0.z; o[3] = f[3] * s0.w + h0.w;
  o[4] = f[4] * s1.x + h1.x; o[5] = f[5] * s1.y + h1.y;
  o[6] = f[6] * s1.z + h1.z; o[7] = f[7] * s1.w + h1.w;
#pragma unroll
  for (int k = 0; k < 8; ++k) {
    float a = o[k];
    a = (a > 0.f) ? a : NEG * a;
    o[k] = d * a;
  }
  uint4 r;
  r.x = pack2(o[0], o[1]); r.y = pack2(o[2], o[3]);
  r.z = pack2(o[4], o[5]); r.w = pack2(o[6], o[7]);
  ((uint4*)z)[idx] = r;
}

// a[i] = dis[i]*(u[i] + sum_{j in N(i)} u[j]); D = 8*VPN bf16/row
template <int VPN>
__global__ void k_agg(const u16* __restrict__ u, const int* __restrict__ rowoff,
                      const int* __restrict__ col, const float* __restrict__ dis,
                      u16* __restrict__ a, int n) {
  int t = blockIdx.x * blockDim.x + threadIdx.x;
  int node = t / VPN;
  int lane = t % VPN;
  if (node >= n) return;
  const uint4* u4 = (const uint4*)u;
  float acc[8];
  {
    uint4 v = u4[(size_t)node * VPN + lane];
    unpack8(v, acc);
  }
  int beg = rowoff[node], end = rowoff[node + 1];
  for (int e = beg; e < end; ++e) {
    int j = col[e];
    uint4 v = u4[(size_t)j * VPN + lane];
    float f[8];
    unpack8(v, f);
#pragma unroll
    for (int k = 0; k < 8; ++k) acc[k] += f[k];
  }
  float d = dis[node];
  uint4 r;
  r.x = pack2(d * acc[0], d * acc[1]);
  r.y = pack2(d * acc[2], d * acc[3]);
  r.z = pack2(d * acc[4], d * acc[5]);
  r.w = pack2(d * acc[6], d * acc[7]);
  ((uint4*)a)[(size_t)node * VPN + lane] = r;
}

// C[n,Fo](bf16) = A[n,K](bf16) @ W[K,Fo](f32) + bias; K%32==0, Fo%64==0
__global__ __launch_bounds__(256) void k_gemm(const u16* __restrict__ A,
                                              const float* __restrict__ W,
                                              const float* __restrict__ bias,
                                              u16* __restrict__ C,
                                              int n, int K, int Fo) {
  __shared__ float As[128][36];
  __shared__ float Ws[32][64];
  int tid = threadIdx.x;
  int bm0 = blockIdx.x * 128, bn0 = blockIdx.y * 64;
  int tx = tid % 16, ty = tid / 16;
  float acc[8][4];
#pragma unroll
  for (int i = 0; i < 8; ++i)
#pragma unroll
    for (int j = 0; j < 4; ++j) acc[i][j] = 0.0f;

  int lm = tid / 4;           // 0..63
  int lk8 = (tid % 4) * 8;    // 0,8,16,24
  int wk = tid / 16;          // 0..15
  int wc4 = (tid % 16) * 4;

  for (int kt = 0; kt < K; kt += 32) {
#pragma unroll
    for (int r = 0; r < 2; ++r) {
      int m = lm + 64 * r;
      int row = bm0 + m;
      uint4 v = make_uint4(0u, 0u, 0u, 0u);
      if (row < n) v = *(const uint4*)&A[(size_t)row * K + kt + lk8];
      float f[8];
      unpack8(v, f);
      *(float4*)&As[m][lk8]     = make_float4(f[0], f[1], f[2], f[3]);
      *(float4*)&As[m][lk8 + 4] = make_float4(f[4], f[5], f[6], f[7]);
    }
#pragma unroll
    for (int r = 0; r < 2; ++r) {
      int k = wk + 16 * r;
      *(float4*)&Ws[k][wc4] = *(const float4*)&W[(size_t)(kt + k) * Fo + bn0 + wc4];
    }
    __syncthreads();
#pragma unroll
    for (int k4 = 0; k4 < 8; ++k4) {
      float4 wf[4];
#pragma unroll
      for (int kk = 0; kk < 4; ++kk) wf[kk] = *(float4*)&Ws[k4 * 4 + kk][tx * 4];
#pragma unroll
      for (int i = 0; i < 8; ++i) {
        float4 af = *(float4*)&As[ty + 16 * i][k4 * 4];
        acc[i][0] += af.x * wf[0].x + af.y * wf[1].x + af.z * wf[2].x + af.w * wf[3].x;
        acc[i][1] += af.x * wf[0].y + af.y * wf[1].y + af.z * wf[2].y + af.w * wf[3].y;
        acc[i][2] += af.x * wf[0].z + af.y * wf[1].z + af.z * wf[2].z + af.w * wf[3].z;
        acc[i][3] += af.x * wf[0].w + af.y * wf[1].w + af.z * wf[2].w + af.w * wf[3].w;
      }
    }
    __syncthreads();
  }
  float4 bv = *(const float4*)&bias[bn0 + tx * 4];
#pragma unroll
  for (int i = 0; i < 8; ++i) {
    int row = bm0 + ty + 16 * i;
    if (row < n) {
      u32 p0 = pack2(acc[i][0] + bv.x, acc[i][1] + bv.y);
      u32 p1 = pack2(acc[i][2] + bv.z, acc[i][3] + bv.w);
      *(uint2*)&C[(size_t)row * Fo + bn0 + tx * 4] = make_uint2(p0, p1);
    }
  }
}

// column partial sums/sumsq over a row chunk (deterministic fixed-order)
__global__ void k_colred(const u16* __restrict__ z, int Fo, int n, int rowsPerChunk,
                         float* __restrict__ psum, float* __restrict__ psq) {
  int fl = threadIdx.x & 63;
  int rg = threadIdx.x >> 6;
  int f = blockIdx.y * 64 + fl;
  int r0 = blockIdx.x * rowsPerChunk;
  int r1 = min(n, r0 + rowsPerChunk);
  float s = 0.f, sq = 0.f;
  for (int r = r0 + rg; r < r1; r += 4) {
    float v = b2f(z[(size_t)r * Fo + f]);
    s += v;
    sq += v * v;
  }
  __shared__ float ls[4][64], lq[4][64];
  ls[rg][fl] = s; lq[rg][fl] = sq;
  __syncthreads();
  if (rg == 0) {
    float ss = ls[0][fl] + ls[1][fl] + ls[2][fl] + ls[3][fl];
    float qq = lq[0][fl] + lq[1][fl] + lq[2][fl] + lq[3][fl];
    psum[(size_t)blockIdx.x * Fo + f] = ss;
    psq[(size_t)blockIdx.x * Fo + f] = qq;
  }
}

__global__ void k_bnparams(const float* __restrict__ psum, const float* __restrict__ psq,
                           int Fo, int nChunks, int n,
                           const float* __restrict__ g, const float* __restrict__ bt,
                           float* __restrict__ scaleF, float* __restrict__ shiftF) {
  int f = blockIdx.x * blockDim.x + threadIdx.x;
  if (f >= Fo) return;
  float s = 0.f, sq = 0.f;
  for (int c = 0; c < nChunks; ++c) {
    s += psum[(size_t)c * Fo + f];
    sq += psq[(size_t)c * Fo + f];
  }
  float inv = 1.0f / (float)n;
  float mu = s * inv;
  float var = sq * inv - mu * mu;
  float rs = rsqrtf(var + EPS_BN) * g[f];
  scaleF[f] = rs;
  shiftF[f] = bt[f] - mu * rs;
}

// v[i] = dis[i] * sum_f lrelu(z5[i][f]*scale+shift) * w6[f]  (z bf16, 512 wide)
__global__ void k_dot512(const u16* __restrict__ z, const float* __restrict__ scaleF,
                         const float* __restrict__ shiftF, const float* __restrict__ w6,
                         const float* __restrict__ dis, float* __restrict__ v, int n) {
  __shared__ float ws[512], scs[512], shs[512];
  int tid = threadIdx.x;
  for (int i = tid; i < 512; i += 256) { ws[i] = w6[i]; scs[i] = scaleF[i]; shs[i] = shiftF[i]; }
  __syncthreads();
  int lane = tid % 64, wv = tid / 64;
  int node = blockIdx.x * 4 + wv;
  if (node >= n) return;
  uint4 vz = *(const uint4*)&z[(size_t)node * 512 + lane * 8];
  float f[8];
  unpack8(vz, f);
  int f0 = lane * 8;
  float s = 0.f;
#pragma unroll
  for (int k = 0; k < 8; ++k) {
    float a = f[k] * scs[f0 + k] + shs[f0 + k];
    a = (a > 0.f) ? a : NEG * a;
    s += a * ws[f0 + k];
  }
#pragma unroll
  for (int off = 32; off > 0; off >>= 1) s += __shfl_down(s, off);
  if (lane == 0) v[node] = dis[node] * s;
}

__global__ void k_final(const float* __restrict__ v, const int* __restrict__ rowoff,
                        const int* __restrict__ col, const float* __restrict__ dis,
                        const float* __restrict__ b6, float* __restrict__ out, int n) {
  int i = blockIdx.x * blockDim.x + threadIdx.x;
  if (i >= n) return;
  float acc = v[i];
  int beg = rowoff[i], end = rowoff[i + 1];
  for (int e = beg; e < end; ++e) acc += v[col[e]];
  float zz = dis[i] * acc + b6[0];
  out[i] = 1.0f / (1.0f + expf(-zz));
}

// ---------------- driver ----------------

extern "C" void kernel_launch(void* const* d_in, const int* in_sizes, int n_in,
                              void* d_out, int out_size, void* d_ws, size_t ws_size,
                              hipStream_t stream) {
  const float* x = (const float*)d_in[0];
  const int* ei = (const int*)d_in[1];
  const int N = in_sizes[0] / 3;
  const int E = in_sizes[1] / 2;
  const int* srcIdx = ei;
  const int* dstIdx = ei + E;

  const float* W[6]; const float* b[6];
  for (int i = 0; i < 6; ++i) { W[i] = (const float*)d_in[2 + 2 * i]; b[i] = (const float*)d_in[3 + 2 * i]; }
  const float* g[5]; const float* bt[5];
  for (int i = 0; i < 5; ++i) { g[i] = (const float*)d_in[14 + 2 * i]; bt[i] = (const float*)d_in[15 + 2 * i]; }

  char* wsB = (char*)d_ws;
  size_t off = 0;
  auto alloc = [&](size_t bytes) -> void* {
    void* p = wsB + off;
    off = (off + bytes + 255) & ~(size_t)255;
    return p;
  };

  int* deg = (int*)alloc((size_t)N * 4);
  int* rowoff = (int*)alloc((size_t)(N + 1) * 4);
  int* cursor = (int*)alloc((size_t)N * 4);
  int* col = (int*)alloc((size_t)E * 4);
  float* dis = (float*)alloc((size_t)N * 4);
  float* vbuf = (float*)alloc((size_t)N * 4);
  float* scaleF = (float*)alloc(512 * 4);
  float* shiftF = (float*)alloc(512 * 4);
  const int rowsPerChunk = 2048;
  const int nChunks = cdiv(N, rowsPerChunk);
  float* psum = (float*)alloc((size_t)nChunks * 512 * 4);
  float* psq = (float*)alloc((size_t)nChunks * 512 * 4);
  u16* Zb = (u16*)alloc((size_t)N * 512 * 2);   // z (and u, in place)
  u16* Ab = (u16*)alloc((size_t)N * 256 * 2);   // aggregated features

  // CSR build + dis
  k_zero_i32<<<cdiv(N, 256), 256, 0, stream>>>(deg, N);
  k_zero_i32<<<cdiv(N, 256), 256, 0, stream>>>(cursor, N);
  k_hist<<<cdiv(E, 256), 256, 0, stream>>>(dstIdx, deg, E);
  k_scan<<<1, 1024, 0, stream>>>(deg, rowoff, N);
  k_fill<<<cdiv(E, 256), 256, 0, stream>>>(srcIdx, dstIdx, rowoff, cursor, col, E);
  k_dis<<<cdiv(N, 256), 256, 0, stream>>>(deg, dis, N);

  auto colred = [&](u16* z, int Fo, int layer) {
    dim3 grid(nChunks, Fo / 64);
    k_colred<<<grid, 256, 0, stream>>>(z, Fo, N, rowsPerChunk, psum, psq);
    k_bnparams<<<1, 512, 0, stream>>>(psum, psq, Fo, nChunks, N,
                                      g[layer], bt[layer], scaleF, shiftF);
  };

  // ---- L1: u1(dim4) -> agg -> gemm(3->64) ----
  k_u1<<<cdiv(N, 256), 256, 0, stream>>>(x, dis, Zb, N);
  k_agg1<<<cdiv(N, 256), 256, 0, stream>>>(Zb, rowoff, col, dis, Ab, N);
  k_gemm1<<<cdiv(N, 4), 256, 0, stream>>>(Ab, W[0], b[0], Zb, N);
  colred(Zb, 64, 0);

  // ---- L2: u(64) in-place -> agg(64) -> gemm(64->64) ----
  k_u<<<cdiv(N * 8, 256), 256, 0, stream>>>(Zb, scaleF, shiftF, dis, N, 3);
  k_agg<8><<<cdiv(N * 8, 256), 256, 0, stream>>>(Zb, rowoff, col, dis, Ab, N);
  k_gemm<<<dim3(cdiv(N, 128), 1), 256, 0, stream>>>(Ab, W[1], b[1], Zb, N, 64, 64);
  colred(Zb, 64, 1);

  // ---- L3: u(64) -> agg(64) -> gemm(64->256) ----
  k_u<<<cdiv(N * 8, 256), 256, 0, stream>>>(Zb, scaleF, shiftF, dis, N, 3);
  k_agg<8><<<cdiv(N * 8, 256), 256, 0, stream>>>(Zb, rowoff, col, dis, Ab, N);
  k_gemm<<<dim3(cdiv(N, 128), 4), 256, 0, stream>>>(Ab, W[2], b[2], Zb, N, 64, 256);
  colred(Zb, 256, 2);

  // ---- L4: u(256) -> agg(256) -> gemm(256->256) ----
  k_u<<<cdiv(N * 32, 256), 256, 0, stream>>>(Zb, scaleF, shiftF, dis, N, 5);
  k_agg<32><<<cdiv(N * 32, 256), 256, 0, stream>>>(Zb, rowoff, col, dis, Ab, N);
  k_gemm<<<dim3(cdiv(N, 128), 4), 256, 0, stream>>>(Ab, W[3], b[3], Zb, N, 256, 256);
  colred(Zb, 256, 3);

  // ---- L5: u(256) -> agg(256) -> gemm(256->512) ----
  k_u<<<cdiv(N * 32, 256), 256, 0, stream>>>(Zb, scaleF, shiftF, dis, N, 5);
  k_agg<32><<<cdiv(N * 32, 256), 256, 0, stream>>>(Zb, rowoff, col, dis, Ab, N);
  k_gemm<<<dim3(cdiv(N, 128), 8), 256, 0, stream>>>(Ab, W[4], b[4], Zb, N, 256, 512);
  colred(Zb, 512, 4);

  // ---- L6: fused bn/lrelu dot(512->1) -> scalar agg -> sigmoid ----
  k_dot512<<<cdiv(N, 4), 256, 0, stream>>>(Zb, scaleF, shiftF, W[5], dis, vbuf, N);
  k_final<<<cdiv(N, 256), 256, 0, stream>>>(vbuf, rowoff, col, dis, b[5], (float*)d_out, N);
}

// Round 3
// 2198.818 us; speedup vs baseline: 1.2284x; 1.2284x over previous
//
#include <hip/hip_runtime.h>
#include <math.h>

typedef unsigned short u16;
typedef unsigned int u32;
typedef __attribute__((ext_vector_type(8))) short bf16x8;
typedef __attribute__((ext_vector_type(4))) float f32x4;

constexpr float EPS_BN = 1e-5f;
constexpr float NEG = 0.1f;

static inline int cdiv(int a, int b) { return (a + b - 1) / b; }

// ---------------- bf16 helpers ----------------

__device__ __forceinline__ float b2f_lo(u32 v) { return __uint_as_float(v << 16); }
__device__ __forceinline__ float b2f_hi(u32 v) { return __uint_as_float(v & 0xFFFF0000u); }
__device__ __forceinline__ float b2f(u16 v) { return __uint_as_float(((u32)v) << 16); }
__device__ __forceinline__ u16 f2b(float f) {
  u32 u = __float_as_uint(f);
  u32 r = u + 0x7FFFu + ((u >> 16) & 1u);
  return (u16)(r >> 16);
}
__device__ __forceinline__ u32 pack2(float a, float b) {
  return (u32)f2b(a) | ((u32)f2b(b) << 16);
}
__device__ __forceinline__ void unpack8(uint4 v, float* o) {
  o[0] = b2f_lo(v.x); o[1] = b2f_hi(v.x);
  o[2] = b2f_lo(v.y); o[3] = b2f_hi(v.y);
  o[4] = b2f_lo(v.z); o[5] = b2f_hi(v.z);
  o[6] = b2f_lo(v.w); o[7] = b2f_hi(v.w);
}
__device__ __forceinline__ void unpack4(uint2 v, float* o) {
  o[0] = b2f_lo(v.x); o[1] = b2f_hi(v.x);
  o[2] = b2f_lo(v.y); o[3] = b2f_hi(v.y);
}

// ---------------- CSR build ----------------

__global__ void k_zero_i32(int* p, int n) {
  int i = blockIdx.x * blockDim.x + threadIdx.x;
  if (i < n) p[i] = 0;
}

__global__ void k_hist(const int* __restrict__ dst, int* __restrict__ deg, int n) {
  int i = blockIdx.x * blockDim.x + threadIdx.x;
  if (i < n) atomicAdd(&deg[dst[i]], 1);
}

__global__ void k_scan(const int* __restrict__ deg, int* __restrict__ rowoff, int n) {
  __shared__ int s[1024];
  __shared__ int carry;
  int tid = threadIdx.x;
  if (tid == 0) { carry = 0; rowoff[0] = 0; }
  __syncthreads();
  for (int base = 0; base < n; base += 4096) {
    int idx = base + tid * 4;
    int v0 = (idx     < n) ? deg[idx]     : 0;
    int v1 = (idx + 1 < n) ? deg[idx + 1] : 0;
    int v2 = (idx + 2 < n) ? deg[idx + 2] : 0;
    int v3 = (idx + 3 < n) ? deg[idx + 3] : 0;
    int ts = v0 + v1 + v2 + v3;
    s[tid] = ts;
    __syncthreads();
    for (int off = 1; off < 1024; off <<= 1) {
      int t = (tid >= off) ? s[tid - off] : 0;
      __syncthreads();
      s[tid] += t;
      __syncthreads();
    }
    int excl = s[tid] - ts;
    int c = carry;
    int p0 = c + excl + v0;
    int p1 = p0 + v1, p2 = p1 + v2, p3 = p2 + v3;
    if (idx + 1 <= n) rowoff[idx + 1] = p0;
    if (idx + 2 <= n) rowoff[idx + 2] = p1;
    if (idx + 3 <= n) rowoff[idx + 3] = p2;
    if (idx + 4 <= n) rowoff[idx + 4] = p3;
    __syncthreads();
    if (tid == 1023) carry = c + s[1023];
    __syncthreads();
  }
}

__global__ void k_fill(const int* __restrict__ src, const int* __restrict__ dst,
                       const int* __restrict__ rowoff, int* __restrict__ cursor,
                       int* __restrict__ col, int n) {
  int i = blockIdx.x * blockDim.x + threadIdx.x;
  if (i < n) {
    int d = dst[i];
    int p = atomicAdd(&cursor[d], 1);
    col[rowoff[d] + p] = src[i];
  }
}

__global__ void k_dis(const int* __restrict__ deg, float* __restrict__ dis, int n) {
  int i = blockIdx.x * blockDim.x + threadIdx.x;
  if (i < n) dis[i] = rsqrtf((float)deg[i] + 1.0f);
}

// ---------------- L1 pieces ----------------

__global__ void k_u1(const float* __restrict__ x, const float* __restrict__ dis,
                     u16* __restrict__ u, int n) {
  int i = blockIdx.x * blockDim.x + threadIdx.x;
  if (i >= n) return;
  float d = dis[i];
  u32 p0 = pack2(d * x[i * 3 + 0], d * x[i * 3 + 1]);
  u32 p1 = pack2(d * x[i * 3 + 2], 0.0f);
  ((uint2*)u)[i] = make_uint2(p0, p1);
}

// wave per node, 64 edges in flight
__global__ void k_agg1(const u16* __restrict__ u, const int* __restrict__ rowoff,
                       const int* __restrict__ col, const float* __restrict__ dis,
                       u16* __restrict__ a, int n) {
  int wid = (blockIdx.x * blockDim.x + threadIdx.x) >> 6;
  int lane = threadIdx.x & 63;
  if (wid >= n) return;
  const uint2* u2 = (const uint2*)u;
  float a0 = 0.f, a1 = 0.f, a2 = 0.f;
  int beg = rowoff[wid], end = rowoff[wid + 1];
  for (int e = beg + lane; e < end; e += 64) {
    uint2 w = u2[col[e]];
    a0 += b2f_lo(w.x); a1 += b2f_hi(w.x); a2 += b2f_lo(w.y);
  }
#pragma unroll
  for (int off = 32; off; off >>= 1) {
    a0 += __shfl_xor(a0, off); a1 += __shfl_xor(a1, off); a2 += __shfl_xor(a2, off);
  }
  if (lane == 0) {
    uint2 s = u2[wid];
    a0 += b2f_lo(s.x); a1 += b2f_hi(s.x); a2 += b2f_lo(s.y);
    float d = dis[wid];
    ((uint2*)a)[wid] = make_uint2(pack2(d * a0, d * a1), pack2(d * a2, 0.0f));
  }
}

__global__ void k_gemm1(const u16* __restrict__ a, const float* __restrict__ W,
                        const float* __restrict__ b, u16* __restrict__ z, int n) {
  __shared__ float Ws[3][64];
  __shared__ float bs[64];
  int tid = threadIdx.x;
  if (tid < 192) Ws[tid / 64][tid % 64] = W[tid];
  if (tid < 64) bs[tid] = b[tid];
  __syncthreads();
  int f = tid % 64, r = tid / 64;
  int node = blockIdx.x * 4 + r;
  if (node >= n) return;
  uint2 v = ((const uint2*)a)[node];
  float a0 = b2f_lo(v.x), a1 = b2f_hi(v.x), a2 = b2f_lo(v.y);
  float zv = a0 * Ws[0][f] + a1 * Ws[1][f] + a2 * Ws[2][f] + bs[f];
  z[(size_t)node * 64 + f] = f2b(zv);
}

// ---------------- aggregations ----------------

// D=64 bf16: wave per node, 4 edges/iter (16 lanes x uint2 each)
__global__ void k_agg64(const u16* __restrict__ u, const int* __restrict__ rowoff,
                        const int* __restrict__ col, const float* __restrict__ dis,
                        u16* __restrict__ a, int n) {
  int wid = (blockIdx.x * blockDim.x + threadIdx.x) >> 6;
  int lane = threadIdx.x & 63;
  if (wid >= n) return;
  int sub = lane >> 4, c = lane & 15;
  const uint2* u2 = (const uint2*)u;
  float acc[4] = {0.f, 0.f, 0.f, 0.f};
  if (sub == 0) {
    float s[4]; unpack4(u2[(size_t)wid * 16 + c], s);
#pragma unroll
    for (int k = 0; k < 4; ++k) acc[k] = s[k];
  }
  int beg = rowoff[wid], end = rowoff[wid + 1];
  for (int e = beg + sub; e < end; e += 4) {
    int j = col[e];
    float f[4]; unpack4(u2[(size_t)j * 16 + c], f);
#pragma unroll
    for (int k = 0; k < 4; ++k) acc[k] += f[k];
  }
#pragma unroll
  for (int k = 0; k < 4; ++k) {
    acc[k] += __shfl_xor(acc[k], 16);
    acc[k] += __shfl_xor(acc[k], 32);
  }
  if (sub == 0) {
    float d = dis[wid];
    ((uint2*)a)[(size_t)wid * 16 + c] =
        make_uint2(pack2(d * acc[0], d * acc[1]), pack2(d * acc[2], d * acc[3]));
  }
}

// D=256 bf16: wave per node, 2 edges/iter (32 lanes x uint4 each)
__global__ void k_agg256(const u16* __restrict__ u, const int* __restrict__ rowoff,
                         const int* __restrict__ col, const float* __restrict__ dis,
                         u16* __restrict__ a, int n) {
  int wid = (blockIdx.x * blockDim.x + threadIdx.x) >> 6;
  int lane = threadIdx.x & 63;
  if (wid >= n) return;
  int sub = lane >> 5, c = lane & 31;
  const uint4* u4 = (const uint4*)u;
  float acc[8] = {0.f, 0.f, 0.f, 0.f, 0.f, 0.f, 0.f, 0.f};
  if (sub == 0) {
    float s[8]; unpack8(u4[(size_t)wid * 32 + c], s);
#pragma unroll
    for (int k = 0; k < 8; ++k) acc[k] = s[k];
  }
  int beg = rowoff[wid], end = rowoff[wid + 1];
  for (int e = beg + sub; e < end; e += 2) {
    int j = col[e];
    float f[8]; unpack8(u4[(size_t)j * 32 + c], f);
#pragma unroll
    for (int k = 0; k < 8; ++k) acc[k] += f[k];
  }
#pragma unroll
  for (int k = 0; k < 8; ++k) acc[k] += __shfl_xor(acc[k], 32);
  if (sub == 0) {
    float d = dis[wid];
    uint4 r;
    r.x = pack2(d * acc[0], d * acc[1]);
    r.y = pack2(d * acc[2], d * acc[3]);
    r.z = pack2(d * acc[4], d * acc[5]);
    r.w = pack2(d * acc[6], d * acc[7]);
    ((uint4*)a)[(size_t)wid * 32 + c] = r;
  }
}

// ---------------- BN fold + elementwise ----------------

__global__ void k_u(u16* __restrict__ z, const float* __restrict__ scaleF,
                    const float* __restrict__ shiftF, const float* __restrict__ dis,
                    int n, int lg) {
  size_t idx = (size_t)blockIdx.x * blockDim.x + threadIdx.x;
  size_t tot = ((size_t)n) << lg;
  if (idx >= tot) return;
  int g = (int)(idx & ((1u << lg) - 1));
  int node = (int)(idx >> lg);
  uint4 v = ((const uint4*)z)[idx];
  float f[8];
  unpack8(v, f);
  int f0 = g * 8;
  float4 s0 = *(const float4*)&scaleF[f0];
  float4 s1 = *(const float4*)&scaleF[f0 + 4];
  float4 h0 = *(const float4*)&shiftF[f0];
  float4 h1 = *(const float4*)&shiftF[f0 + 4];
  float d = dis[node];
  float o[8];
  o[0] = f[0] * s0.x + h0.x; o[1] = f[1] * s0.y + h0.y;
  o[2] = f[2] * s0.z + h0.z; o[3] = f[3] * s0.w + h0.w;
  o[4] = f[4] * s1.x + h1.x; o[5] = f[5] * s1.y + h1.y;
  o[6] = f[6] * s1.z + h1.z; o[7] = f[7] * s1.w + h1.w;
#pragma unroll
  for (int k = 0; k < 8; ++k) {
    float a = o[k];
    a = (a > 0.f) ? a : NEG * a;
    o[k] = d * a;
  }
  uint4 r;
  r.x = pack2(o[0], o[1]); r.y = pack2(o[2], o[3]);
  r.z = pack2(o[4], o[5]); r.w = pack2(o[6], o[7]);
  ((uint4*)z)[idx] = r;
}

// ---------------- MFMA GEMM ----------------

// WT[f][k] = bf16(W[k][f])
__global__ void k_wt(const float* __restrict__ W, u16* __restrict__ WT, int K, int Fo) {
  int i = blockIdx.x * blockDim.x + threadIdx.x;
  if (i >= K * Fo) return;
  int f = i / K, k = i - f * K;
  WT[i] = f2b(W[(size_t)k * Fo + f]);
}

// C[n,Fo](bf16) = A[n,K](bf16) @ WT[Fo,K]^T + bias ; K%64==0, 16x16x32 MFMA
__global__ __launch_bounds__(256) void k_gemm(const u16* __restrict__ A,
                                              const u16* __restrict__ WT,
                                              const float* __restrict__ bias,
                                              u16* __restrict__ C,
                                              int n, int K, int Fo, int nby) {
  __shared__ u16 As[128][72];   // +8 pad: bank-uniform for b128 frag reads
  __shared__ u16 Bs[128][72];
  int tid = threadIdx.x;
  int nwg = gridDim.x;
  int bid = blockIdx.x;
  // bijective XCD chunking; y-fastest within chunk -> A-panel L2 reuse
  int q = nwg >> 3, rr = nwg & 7;
  int xcd = bid & 7, pos = bid >> 3;
  int wgid = (xcd < rr ? xcd * (q + 1) : rr * (q + 1) + (xcd - rr) * q) + pos;
  int bx = wgid / nby, by = wgid - bx * nby;
  int bm0 = bx * 128, bn0 = by * 128;
  int lane = tid & 63, wid = tid >> 6;
  int wm = wid >> 1, wn = wid & 1;
  int lr = tid & 127;
  int lh = (tid >> 7) * 32;
  int fr = lane & 15, fg = lane >> 4;
  f32x4 acc[4][4];
#pragma unroll
  for (int i = 0; i < 4; ++i)
#pragma unroll
    for (int j = 0; j < 4; ++j) acc[i][j] = (f32x4)0.0f;

  for (int kt = 0; kt < K; kt += 64) {
    {
      int row = bm0 + lr;
      uint4 v[4];
#pragma unroll
      for (int i = 0; i < 4; ++i) {
        v[i] = make_uint4(0u, 0u, 0u, 0u);
        if (row < n) v[i] = *(const uint4*)&A[(size_t)row * K + kt + lh + i * 8];
      }
      int fo = bn0 + lr;
      uint4 w[4];
#pragma unroll
      for (int i = 0; i < 4; ++i) {
        w[i] = make_uint4(0u, 0u, 0u, 0u);
        if (fo < Fo) w[i] = *(const uint4*)&WT[(size_t)fo * K + kt + lh + i * 8];
      }
#pragma unroll
      for (int i = 0; i < 4; ++i) *(uint4*)&As[lr][lh + i * 8] = v[i];
#pragma unroll
      for (int i = 0; i < 4; ++i) *(uint4*)&Bs[lr][lh + i * 8] = w[i];
    }
    __syncthreads();
#pragma unroll
    for (int ks = 0; ks < 2; ++ks) {
      int k0 = ks * 32 + fg * 8;
      bf16x8 af[4], bf[4];
#pragma unroll
      for (int mi = 0; mi < 4; ++mi) af[mi] = *(const bf16x8*)&As[wm * 64 + mi * 16 + fr][k0];
#pragma unroll
      for (int ni = 0; ni < 4; ++ni) bf[ni] = *(const bf16x8*)&Bs[wn * 64 + ni * 16 + fr][k0];
#pragma unroll
      for (int mi = 0; mi < 4; ++mi)
#pragma unroll
        for (int ni = 0; ni < 4; ++ni)
          acc[mi][ni] = __builtin_amdgcn_mfma_f32_16x16x32_bf16(af[mi], bf[ni], acc[mi][ni], 0, 0, 0);
    }
    __syncthreads();
  }
#pragma unroll
  for (int ni = 0; ni < 4; ++ni) {
    int gc = bn0 + wn * 64 + ni * 16 + fr;
    if (gc >= Fo) continue;
    float bv = bias[gc];
#pragma unroll
    for (int mi = 0; mi < 4; ++mi) {
#pragma unroll
      for (int rg = 0; rg < 4; ++rg) {
        int gr = bm0 + wm * 64 + mi * 16 + fg * 4 + rg;
        if (gr < n) C[(size_t)gr * Fo + gc] = f2b(acc[mi][ni][rg] + bv);
      }
    }
  }
}

// ---------------- BN stats ----------------

__global__ void k_colred(const u16* __restrict__ z, int Fo, int n, int rowsPerChunk,
                         float* __restrict__ psum, float* __restrict__ psq) {
  int fl = threadIdx.x & 63;
  int rg = threadIdx.x >> 6;
  int f = blockIdx.y * 64 + fl;
  int r0 = blockIdx.x * rowsPerChunk;
  int r1 = min(n, r0 + rowsPerChunk);
  float s = 0.f, sq = 0.f;
  for (int r = r0 + rg; r < r1; r += 4) {
    float v = b2f(z[(size_t)r * Fo + f]);
    s += v;
    sq += v * v;
  }
  __shared__ float ls[4][64], lq[4][64];
  ls[rg][fl] = s; lq[rg][fl] = sq;
  __syncthreads();
  if (rg == 0) {
    float ss = ls[0][fl] + ls[1][fl] + ls[2][fl] + ls[3][fl];
    float qq = lq[0][fl] + lq[1][fl] + lq[2][fl] + lq[3][fl];
    psum[(size_t)blockIdx.x * Fo + f] = ss;
    psq[(size_t)blockIdx.x * Fo + f] = qq;
  }
}

__global__ void k_bnparams(const float* __restrict__ psum, const float* __restrict__ psq,
                           int Fo, int nChunks, int n,
                           const float* __restrict__ g, const float* __restrict__ bt,
                           float* __restrict__ scaleF, float* __restrict__ shiftF) {
  int f = blockIdx.x * blockDim.x + threadIdx.x;
  if (f >= Fo) return;
  float s = 0.f, sq = 0.f;
  for (int c = 0; c < nChunks; ++c) {
    s += psum[(size_t)c * Fo + f];
    sq += psq[(size_t)c * Fo + f];
  }
  float inv = 1.0f / (float)n;
  float mu = s * inv;
  float var = sq * inv - mu * mu;
  float rs = rsqrtf(var + EPS_BN) * g[f];
  scaleF[f] = rs;
  shiftF[f] = bt[f] - mu * rs;
}

// ---------------- final layer ----------------

__global__ void k_dot512(const u16* __restrict__ z, const float* __restrict__ scaleF,
                         const float* __restrict__ shiftF, const float* __restrict__ w6,
                         const float* __restrict__ dis, float* __restrict__ v, int n) {
  __shared__ float ws[512], scs[512], shs[512];
  int tid = threadIdx.x;
  for (int i = tid; i < 512; i += 256) { ws[i] = w6[i]; scs[i] = scaleF[i]; shs[i] = shiftF[i]; }
  __syncthreads();
  int lane = tid % 64, wv = tid / 64;
  int node = blockIdx.x * 4 + wv;
  if (node >= n) return;
  uint4 vz = *(const uint4*)&z[(size_t)node * 512 + lane * 8];
  float f[8];
  unpack8(vz, f);
  int f0 = lane * 8;
  float s = 0.f;
#pragma unroll
  for (int k = 0; k < 8; ++k) {
    float a = f[k] * scs[f0 + k] + shs[f0 + k];
    a = (a > 0.f) ? a : NEG * a;
    s += a * ws[f0 + k];
  }
#pragma unroll
  for (int off = 32; off > 0; off >>= 1) s += __shfl_down(s, off);
  if (lane == 0) v[node] = dis[node] * s;
}

__global__ void k_final(const float* __restrict__ v, const int* __restrict__ rowoff,
                        const int* __restrict__ col, const float* __restrict__ dis,
                        const float* __restrict__ b6, float* __restrict__ out, int n) {
  int wid = (blockIdx.x * blockDim.x + threadIdx.x) >> 6;
  int lane = threadIdx.x & 63;
  if (wid >= n) return;
  float acc = 0.f;
  int beg = rowoff[wid], end = rowoff[wid + 1];
  for (int e = beg + lane; e < end; e += 64) acc += v[col[e]];
#pragma unroll
  for (int off = 32; off; off >>= 1) acc += __shfl_xor(acc, off);
  if (lane == 0) {
    float zz = dis[wid] * (acc + v[wid]) + b6[0];
    out[wid] = 1.0f / (1.0f + expf(-zz));
  }
}

// ---------------- driver ----------------

extern "C" void kernel_launch(void* const* d_in, const int* in_sizes, int n_in,
                              void* d_out, int out_size, void* d_ws, size_t ws_size,
                              hipStream_t stream) {
  const float* x = (const float*)d_in[0];
  const int* ei = (const int*)d_in[1];
  const int N = in_sizes[0] / 3;
  const int E = in_sizes[1] / 2;
  const int* srcIdx = ei;
  const int* dstIdx = ei + E;

  const float* W[6]; const float* b[6];
  for (int i = 0; i < 6; ++i) { W[i] = (const float*)d_in[2 + 2 * i]; b[i] = (const float*)d_in[3 + 2 * i]; }
  const float* g[5]; const float* bt[5];
  for (int i = 0; i < 5; ++i) { g[i] = (const float*)d_in[14 + 2 * i]; bt[i] = (const float*)d_in[15 + 2 * i]; }

  char* wsB = (char*)d_ws;
  size_t off = 0;
  auto alloc = [&](size_t bytes) -> void* {
    void* p = wsB + off;
    off = (off + bytes + 255) & ~(size_t)255;
    return p;
  };

  int* deg = (int*)alloc((size_t)N * 4);
  int* rowoff = (int*)alloc((size_t)(N + 1) * 4);
  int* cursor = (int*)alloc((size_t)N * 4);
  int* col = (int*)alloc((size_t)E * 4);
  float* dis = (float*)alloc((size_t)N * 4);
  float* vbuf = (float*)alloc((size_t)N * 4);
  float* scaleF = (float*)alloc(512 * 4);
  float* shiftF = (float*)alloc(512 * 4);
  u16* WTb = (u16*)alloc((size_t)512 * 256 * 2);
  const int rowsPerChunk = 2048;
  const int nChunks = cdiv(N, rowsPerChunk);
  float* psum = (float*)alloc((size_t)nChunks * 512 * 4);
  float* psq = (float*)alloc((size_t)nChunks * 512 * 4);
  u16* Zb = (u16*)alloc((size_t)N * 512 * 2);   // z (and u, in place)
  u16* Ab = (u16*)alloc((size_t)N * 256 * 2);   // aggregated features

  // CSR build + dis
  k_zero_i32<<<cdiv(N, 256), 256, 0, stream>>>(deg, N);
  k_zero_i32<<<cdiv(N, 256), 256, 0, stream>>>(cursor, N);
  k_hist<<<cdiv(E, 256), 256, 0, stream>>>(dstIdx, deg, E);
  k_scan<<<1, 1024, 0, stream>>>(deg, rowoff, N);
  k_fill<<<cdiv(E, 256), 256, 0, stream>>>(srcIdx, dstIdx, rowoff, cursor, col, E);
  k_dis<<<cdiv(N, 256), 256, 0, stream>>>(deg, dis, N);

  const int nbx = cdiv(N, 128);
  auto gemm = [&](const u16* Ain, int layer, int K, int Fo, u16* Cout) {
    k_wt<<<cdiv(K * Fo, 256), 256, 0, stream>>>(W[layer], WTb, K, Fo);
    int nby = cdiv(Fo, 128);
    k_gemm<<<nbx * nby, 256, 0, stream>>>(Ain, WTb, b[layer], Cout, N, K, Fo, nby);
  };
  auto colred = [&](u16* z, int Fo, int layer) {
    dim3 grid(nChunks, Fo / 64);
    k_colred<<<grid, 256, 0, stream>>>(z, Fo, N, rowsPerChunk, psum, psq);
    k_bnparams<<<1, 512, 0, stream>>>(psum, psq, Fo, nChunks, N,
                                      g[layer], bt[layer], scaleF, shiftF);
  };

  const int waveGrid = cdiv(N * 64, 256);

  // ---- L1: u1 -> agg(d3) -> gemm(3->64) ----
  k_u1<<<cdiv(N, 256), 256, 0, stream>>>(x, dis, Zb, N);
  k_agg1<<<waveGrid, 256, 0, stream>>>(Zb, rowoff, col, dis, Ab, N);
  k_gemm1<<<cdiv(N, 4), 256, 0, stream>>>(Ab, W[0], b[0], Zb, N);
  colred(Zb, 64, 0);

  // ---- L2 ----
  k_u<<<cdiv(N * 8, 256), 256, 0, stream>>>(Zb, scaleF, shiftF, dis, N, 3);
  k_agg64<<<waveGrid, 256, 0, stream>>>(Zb, rowoff, col, dis, Ab, N);
  gemm(Ab, 1, 64, 64, Zb);
  colred(Zb, 64, 1);

  // ---- L3 ----
  k_u<<<cdiv(N * 8, 256), 256, 0, stream>>>(Zb, scaleF, shiftF, dis, N, 3);
  k_agg64<<<waveGrid, 256, 0, stream>>>(Zb, rowoff, col, dis, Ab, N);
  gemm(Ab, 2, 64, 256, Zb);
  colred(Zb, 256, 2);

  // ---- L4 ----
  k_u<<<cdiv(N * 32, 256), 256, 0, stream>>>(Zb, scaleF, shiftF, dis, N, 5);
  k_agg256<<<waveGrid, 256, 0, stream>>>(Zb, rowoff, col, dis, Ab, N);
  gemm(Ab, 3, 256, 256, Zb);
  colred(Zb, 256, 3);

  // ---- L5 ----
  k_u<<<cdiv(N * 32, 256), 256, 0, stream>>>(Zb, scaleF, shiftF, dis, N, 5);
  k_agg256<<<waveGrid, 256, 0, stream>>>(Zb, rowoff, col, dis, Ab, N);
  gemm(Ab, 4, 256, 512, Zb);
  colred(Zb, 512, 4);

  // ---- L6 ----
  k_dot512<<<cdiv(N, 4), 256, 0, stream>>>(Zb, scaleF, shiftF, W[5], dis, vbuf, N);
  k_final<<<waveGrid, 256, 0, stream>>>(vbuf, rowoff, col, dis, b[5], (float*)d_out, N);
}

// Round 4
// 2090.838 us; speedup vs baseline: 1.2919x; 1.0516x over previous
//
#include <hip/hip_runtime.h>
#include <math.h>

typedef unsigned short u16;
typedef unsigned int u32;
typedef __attribute__((ext_vector_type(8))) short bf16x8;
typedef __attribute__((ext_vector_type(4))) float f32x4;

constexpr float EPS_BN = 1e-5f;
constexpr float NEG = 0.1f;

static inline int cdiv(int a, int b) { return (a + b - 1) / b; }

// ---------------- bf16 helpers ----------------

__device__ __forceinline__ float b2f_lo(u32 v) { return __uint_as_float(v << 16); }
__device__ __forceinline__ float b2f_hi(u32 v) { return __uint_as_float(v & 0xFFFF0000u); }
__device__ __forceinline__ float b2f(u16 v) { return __uint_as_float(((u32)v) << 16); }
__device__ __forceinline__ u16 f2b(float f) {
  u32 u = __float_as_uint(f);
  u32 r = u + 0x7FFFu + ((u >> 16) & 1u);
  return (u16)(r >> 16);
}
__device__ __forceinline__ u32 pack2(float a, float b) {
  return (u32)f2b(a) | ((u32)f2b(b) << 16);
}
__device__ __forceinline__ void unpack8(uint4 v, float* o) {
  o[0] = b2f_lo(v.x); o[1] = b2f_hi(v.x);
  o[2] = b2f_lo(v.y); o[3] = b2f_hi(v.y);
  o[4] = b2f_lo(v.z); o[5] = b2f_hi(v.z);
  o[6] = b2f_lo(v.w); o[7] = b2f_hi(v.w);
}
__device__ __forceinline__ void unpack4(uint2 v, float* o) {
  o[0] = b2f_lo(v.x); o[1] = b2f_hi(v.x);
  o[2] = b2f_lo(v.y); o[3] = b2f_hi(v.y);
}

// ---------------- CSR build (bucketed, low write-amplification) ----------------

__global__ void k_zero_i32(int* p, int n) {
  int i = blockIdx.x * blockDim.x + threadIdx.x;
  if (i < n) p[i] = 0;
}

// per-block LDS histogram of dst>>9, flush to global bucketCnt
__global__ __launch_bounds__(256) void k_bcount(const int* __restrict__ dst,
                                                int* __restrict__ bucketCnt, int E) {
  __shared__ int hist[256];
  int tid = threadIdx.x;
  hist[tid] = 0;
  __syncthreads();
  int e0 = blockIdx.x * 4096;
#pragma unroll
  for (int i = 0; i < 16; ++i) {
    int e = e0 + i * 256 + tid;
    if (e < E) atomicAdd(&hist[dst[e] >> 9], 1);
  }
  __syncthreads();
  int h = hist[tid];
  if (h > 0) atomicAdd(&bucketCnt[tid], h);
}

// scan NB bucket sizes (NB <= 256); also zero bucket cursors
__global__ void k_bscan(const int* __restrict__ bucketCnt, int* __restrict__ bucketOff,
                        int* __restrict__ bucketCur, int NB, int E) {
  __shared__ int s[256];
  int tid = threadIdx.x;
  int v = (tid < NB) ? bucketCnt[tid] : 0;
  s[tid] = v;
  __syncthreads();
  for (int off = 1; off < 256; off <<= 1) {
    int t = (tid >= off) ? s[tid - off] : 0;
    __syncthreads();
    s[tid] += t;
    __syncthreads();
  }
  if (tid < NB) bucketOff[tid] = s[tid] - v;
  if (tid == NB) bucketOff[NB] = E;
  if (tid < NB) bucketCur[tid] = 0;
}

// scatter (src,dst) into bucket regions; per-block reservation per bucket
__global__ __launch_bounds__(256) void k_bucket(const int* __restrict__ src,
                                                const int* __restrict__ dst,
                                                const int* __restrict__ bucketOff,
                                                int* __restrict__ bucketCur,
                                                uint2* __restrict__ ebuf, int E) {
  __shared__ int hist[256];
  __shared__ int base[256];
  __shared__ int lcur[256];
  int tid = threadIdx.x;
  hist[tid] = 0; lcur[tid] = 0;
  __syncthreads();
  int e0 = blockIdx.x * 4096;
  int ss[16], dd[16];
#pragma unroll
  for (int i = 0; i < 16; ++i) {
    int e = e0 + i * 256 + tid;
    if (e < E) {
      ss[i] = src[e]; dd[i] = dst[e];
      atomicAdd(&hist[dd[i] >> 9], 1);
    } else dd[i] = -1;
  }
  __syncthreads();
  int h = hist[tid];
  if (h > 0) base[tid] = bucketOff[tid] + atomicAdd(&bucketCur[tid], h);
  __syncthreads();
#pragma unroll
  for (int i = 0; i < 16; ++i) {
    if (dd[i] >= 0) {
      int bk = dd[i] >> 9;
      int p = atomicAdd(&lcur[bk], 1);
      ebuf[base[bk] + p] = make_uint2((u32)ss[i], (u32)dd[i]);
    }
  }
}

// per-bucket CSR finalize: rowoff, dis, col (writes land in a 64KB L2-hot region)
__global__ __launch_bounds__(256) void k_csr(const uint2* __restrict__ ebuf,
                                             const int* __restrict__ bucketOff,
                                             int* __restrict__ rowoff,
                                             int* __restrict__ col,
                                             float* __restrict__ dis,
                                             int N, int E, int NB) {
  __shared__ int hist[512];
  __shared__ int loff[512];
  __shared__ int scan_s[256];
  int b = blockIdx.x;
  int tid = threadIdx.x;
  int ebase = bucketOff[b], eend = bucketOff[b + 1];
  int ecnt = eend - ebase;
  hist[tid] = 0; hist[tid + 256] = 0;
  __syncthreads();
  for (int i = tid; i < ecnt; i += 256)
    atomicAdd(&hist[ebuf[ebase + i].y & 511], 1);
  __syncthreads();
  int h0 = hist[2 * tid], h1 = hist[2 * tid + 1];
  int ts = h0 + h1;
  scan_s[tid] = ts;
  __syncthreads();
  for (int off = 1; off < 256; off <<= 1) {
    int t = (tid >= off) ? scan_s[tid - off] : 0;
    __syncthreads();
    scan_s[tid] += t;
    __syncthreads();
  }
  int excl = scan_s[tid] - ts;
  loff[2 * tid] = excl;
  loff[2 * tid + 1] = excl + h0;
  __syncthreads();
  int gbase = b * 512;
  for (int i = tid; i < 512; i += 256) {
    int node = gbase + i;
    if (node < N) {
      rowoff[node] = ebase + loff[i];
      dis[node] = rsqrtf((float)hist[i] + 1.0f);
    }
  }
  if (b == NB - 1 && tid == 0) rowoff[N] = E;
  __syncthreads();
  // scatter src into col using loff as cursors
  for (int i = tid; i < ecnt; i += 256) {
    uint2 ed = ebuf[ebase + i];
    int p = atomicAdd(&loff[ed.y & 511], 1);
    col[ebase + p] = (int)ed.x;
  }
}

// ---------------- L1 pieces ----------------

__global__ void k_u1(const float* __restrict__ x, const float* __restrict__ dis,
                     u16* __restrict__ u, int n) {
  int i = blockIdx.x * blockDim.x + threadIdx.x;
  if (i >= n) return;
  float d = dis[i];
  u32 p0 = pack2(d * x[i * 3 + 0], d * x[i * 3 + 1]);
  u32 p1 = pack2(d * x[i * 3 + 2], 0.0f);
  ((uint2*)u)[i] = make_uint2(p0, p1);
}

__global__ void k_agg1(const u16* __restrict__ u, const int* __restrict__ rowoff,
                       const int* __restrict__ col, const float* __restrict__ dis,
                       u16* __restrict__ a, int n) {
  int wid = (blockIdx.x * blockDim.x + threadIdx.x) >> 6;
  int lane = threadIdx.x & 63;
  if (wid >= n) return;
  const uint2* u2 = (const uint2*)u;
  float a0 = 0.f, a1 = 0.f, a2 = 0.f;
  int beg = rowoff[wid], end = rowoff[wid + 1];
  for (int e = beg + lane; e < end; e += 64) {
    uint2 w = u2[col[e]];
    a0 += b2f_lo(w.x); a1 += b2f_hi(w.x); a2 += b2f_lo(w.y);
  }
#pragma unroll
  for (int off = 32; off; off >>= 1) {
    a0 += __shfl_xor(a0, off); a1 += __shfl_xor(a1, off); a2 += __shfl_xor(a2, off);
  }
  if (lane == 0) {
    uint2 s = u2[wid];
    a0 += b2f_lo(s.x); a1 += b2f_hi(s.x); a2 += b2f_lo(s.y);
    float d = dis[wid];
    ((uint2*)a)[wid] = make_uint2(pack2(d * a0, d * a1), pack2(d * a2, 0.0f));
  }
}

__global__ void k_gemm1(const u16* __restrict__ a, const float* __restrict__ W,
                        const float* __restrict__ b, u16* __restrict__ z, int n) {
  __shared__ float Ws[3][64];
  __shared__ float bs[64];
  int tid = threadIdx.x;
  if (tid < 192) Ws[tid / 64][tid % 64] = W[tid];
  if (tid < 64) bs[tid] = b[tid];
  __syncthreads();
  int f = tid % 64, r = tid / 64;
  int node = blockIdx.x * 4 + r;
  if (node >= n) return;
  uint2 v = ((const uint2*)a)[node];
  float a0 = b2f_lo(v.x), a1 = b2f_hi(v.x), a2 = b2f_lo(v.y);
  float zv = a0 * Ws[0][f] + a1 * Ws[1][f] + a2 * Ws[2][f] + bs[f];
  z[(size_t)node * 64 + f] = f2b(zv);
}

// ---------------- aggregations ----------------

// D=64: wave/node, 4 sub-waves of 16 lanes, 2x unrolled -> 8 gathers in flight
__global__ void k_agg64(const u16* __restrict__ u, const int* __restrict__ rowoff,
                        const int* __restrict__ col, const float* __restrict__ dis,
                        u16* __restrict__ a, int n) {
  int wid = (blockIdx.x * blockDim.x + threadIdx.x) >> 6;
  int lane = threadIdx.x & 63;
  if (wid >= n) return;
  int sub = lane >> 4, c = lane & 15;
  const uint2* u2 = (const uint2*)u;
  float acc[4] = {0.f, 0.f, 0.f, 0.f};
  if (sub == 0) {
    float s[4]; unpack4(u2[(size_t)wid * 16 + c], s);
#pragma unroll
    for (int k = 0; k < 4; ++k) acc[k] = s[k];
  }
  int beg = rowoff[wid], end = rowoff[wid + 1];
  int e = beg + sub;
  for (; e + 4 < end; e += 8) {
    int j1 = col[e], j2 = col[e + 4];
    uint2 v1 = u2[(size_t)j1 * 16 + c];
    uint2 v2 = u2[(size_t)j2 * 16 + c];
    float f1[4], f2[4];
    unpack4(v1, f1); unpack4(v2, f2);
#pragma unroll
    for (int k = 0; k < 4; ++k) acc[k] += f1[k] + f2[k];
  }
  if (e < end) {
    float f1[4]; unpack4(u2[(size_t)col[e] * 16 + c], f1);
#pragma unroll
    for (int k = 0; k < 4; ++k) acc[k] += f1[k];
  }
#pragma unroll
  for (int k = 0; k < 4; ++k) {
    acc[k] += __shfl_xor(acc[k], 16);
    acc[k] += __shfl_xor(acc[k], 32);
  }
  if (sub == 0) {
    float d = dis[wid];
    ((uint2*)a)[(size_t)wid * 16 + c] =
        make_uint2(pack2(d * acc[0], d * acc[1]), pack2(d * acc[2], d * acc[3]));
  }
}

// D=256: wave/node, 2 sub-waves of 32 lanes, 2x unrolled -> 4 gathers in flight
__global__ void k_agg256(const u16* __restrict__ u, const int* __restrict__ rowoff,
                         const int* __restrict__ col, const float* __restrict__ dis,
                         u16* __restrict__ a, int n) {
  int wid = (blockIdx.x * blockDim.x + threadIdx.x) >> 6;
  int lane = threadIdx.x & 63;
  if (wid >= n) return;
  int sub = lane >> 5, c = lane & 31;
  const uint4* u4 = (const uint4*)u;
  float acc[8] = {0.f, 0.f, 0.f, 0.f, 0.f, 0.f, 0.f, 0.f};
  if (sub == 0) {
    float s[8]; unpack8(u4[(size_t)wid * 32 + c], s);
#pragma unroll
    for (int k = 0; k < 8; ++k) acc[k] = s[k];
  }
  int beg = rowoff[wid], end = rowoff[wid + 1];
  int e = beg + sub;
  for (; e + 2 < end; e += 4) {
    int j1 = col[e], j2 = col[e + 2];
    uint4 v1 = u4[(size_t)j1 * 32 + c];
    uint4 v2 = u4[(size_t)j2 * 32 + c];
    float f1[8], f2[8];
    unpack8(v1, f1); unpack8(v2, f2);
#pragma unroll
    for (int k = 0; k < 8; ++k) acc[k] += f1[k] + f2[k];
  }
  if (e < end) {
    float f1[8]; unpack8(u4[(size_t)col[e] * 32 + c], f1);
#pragma unroll
    for (int k = 0; k < 8; ++k) acc[k] += f1[k];
  }
#pragma unroll
  for (int k = 0; k < 8; ++k) acc[k] += __shfl_xor(acc[k], 32);
  if (sub == 0) {
    float d = dis[wid];
    uint4 r;
    r.x = pack2(d * acc[0], d * acc[1]);
    r.y = pack2(d * acc[2], d * acc[3]);
    r.z = pack2(d * acc[4], d * acc[5]);
    r.w = pack2(d * acc[6], d * acc[7]);
    ((uint4*)a)[(size_t)wid * 32 + c] = r;
  }
}

// ---------------- BN fold (in-place) ----------------

__global__ void k_u(u16* __restrict__ z, const float* __restrict__ scaleF,
                    const float* __restrict__ shiftF, const float* __restrict__ dis,
                    int n, int lg) {
  size_t idx = (size_t)blockIdx.x * blockDim.x + threadIdx.x;
  size_t tot = ((size_t)n) << lg;
  if (idx >= tot) return;
  int g = (int)(idx & ((1u << lg) - 1));
  int node = (int)(idx >> lg);
  uint4 v = ((const uint4*)z)[idx];
  float f[8];
  unpack8(v, f);
  int f0 = g * 8;
  float4 s0 = *(const float4*)&scaleF[f0];
  float4 s1 = *(const float4*)&scaleF[f0 + 4];
  float4 h0 = *(const float4*)&shiftF[f0];
  float4 h1 = *(const float4*)&shiftF[f0 + 4];
  float d = dis[node];
  float o[8];
  o[0] = f[0] * s0.x + h0.x; o[1] = f[1] * s0.y + h0.y;
  o[2] = f[2] * s0.z + h0.z; o[3] = f[3] * s0.w + h0.w;
  o[4] = f[4] * s1.x + h1.x; o[5] = f[5] * s1.y + h1.y;
  o[6] = f[6] * s1.z + h1.z; o[7] = f[7] * s1.w + h1.w;
#pragma unroll
  for (int k = 0; k < 8; ++k) {
    float a = o[k];
    a = (a > 0.f) ? a : NEG * a;
    o[k] = d * a;
  }
  uint4 r;
  r.x = pack2(o[0], o[1]); r.y = pack2(o[2], o[3]);
  r.z = pack2(o[4], o[5]); r.w = pack2(o[6], o[7]);
  ((uint4*)z)[idx] = r;
}

// ---------------- MFMA GEMM with fused column stats ----------------

__global__ void k_wt(const float* __restrict__ W, u16* __restrict__ WT, int K, int Fo) {
  int i = blockIdx.x * blockDim.x + threadIdx.x;
  if (i >= K * Fo) return;
  int f = i / K, k = i - f * K;
  WT[i] = f2b(W[(size_t)k * Fo + f]);
}

// C[n,Fo](bf16) = A[n,K](bf16) @ WT[Fo,K]^T + bias ; also psum/psq[bx][col]
__global__ __launch_bounds__(256) void k_gemm(const u16* __restrict__ A,
                                              const u16* __restrict__ WT,
                                              const float* __restrict__ bias,
                                              u16* __restrict__ C,
                                              float* __restrict__ psum,
                                              float* __restrict__ psq,
                                              int n, int K, int Fo, int nby) {
  __shared__ u16 As[128][72];
  __shared__ u16 Bs[128][72];
  int tid = threadIdx.x;
  int nwg = gridDim.x;
  int bid = blockIdx.x;
  int q = nwg >> 3, rr = nwg & 7;
  int xcd = bid & 7, pos = bid >> 3;
  int wgid = (xcd < rr ? xcd * (q + 1) : rr * (q + 1) + (xcd - rr) * q) + pos;
  int bx = wgid / nby, by = wgid - bx * nby;
  int bm0 = bx * 128, bn0 = by * 128;
  int lane = tid & 63, wid = tid >> 6;
  int wm = wid >> 1, wn = wid & 1;
  int lr = tid & 127;
  int lh = (tid >> 7) * 32;
  int fr = lane & 15, fg = lane >> 4;
  f32x4 acc[4][4];
#pragma unroll
  for (int i = 0; i < 4; ++i)
#pragma unroll
    for (int j = 0; j < 4; ++j) acc[i][j] = (f32x4)0.0f;

  for (int kt = 0; kt < K; kt += 64) {
    {
      int row = bm0 + lr;
      uint4 v[4];
#pragma unroll
      for (int i = 0; i < 4; ++i) {
        v[i] = make_uint4(0u, 0u, 0u, 0u);
        if (row < n) v[i] = *(const uint4*)&A[(size_t)row * K + kt + lh + i * 8];
      }
      int fo = bn0 + lr;
      uint4 w[4];
#pragma unroll
      for (int i = 0; i < 4; ++i) {
        w[i] = make_uint4(0u, 0u, 0u, 0u);
        if (fo < Fo) w[i] = *(const uint4*)&WT[(size_t)fo * K + kt + lh + i * 8];
      }
#pragma unroll
      for (int i = 0; i < 4; ++i) *(uint4*)&As[lr][lh + i * 8] = v[i];
#pragma unroll
      for (int i = 0; i < 4; ++i) *(uint4*)&Bs[lr][lh + i * 8] = w[i];
    }
    __syncthreads();
#pragma unroll
    for (int ks = 0; ks < 2; ++ks) {
      int k0 = ks * 32 + fg * 8;
      bf16x8 af[4], bf[4];
#pragma unroll
      for (int mi = 0; mi < 4; ++mi) af[mi] = *(const bf16x8*)&As[wm * 64 + mi * 16 + fr][k0];
#pragma unroll
      for (int ni = 0; ni < 4; ++ni) bf[ni] = *(const bf16x8*)&Bs[wn * 64 + ni * 16 + fr][k0];
#pragma unroll
      for (int mi = 0; mi < 4; ++mi)
#pragma unroll
        for (int ni = 0; ni < 4; ++ni)
          acc[mi][ni] = __builtin_amdgcn_mfma_f32_16x16x32_bf16(af[mi], bf[ni], acc[mi][ni], 0, 0, 0);
    }
    __syncthreads();
  }
  // epilogue: C-write + per-block column sum/sumsq (LDS aliased over As)
  float* s2 = (float*)&As[0][0];   // [2][128] sums then [2][128] sumsq
#pragma unroll
  for (int ni = 0; ni < 4; ++ni) {
    int gc = bn0 + wn * 64 + ni * 16 + fr;
    float ps = 0.f, pq = 0.f;
    if (gc < Fo) {
      float bv = bias[gc];
#pragma unroll
      for (int mi = 0; mi < 4; ++mi) {
#pragma unroll
        for (int rg = 0; rg < 4; ++rg) {
          int gr = bm0 + wm * 64 + mi * 16 + fg * 4 + rg;
          if (gr < n) {
            float v = acc[mi][ni][rg] + bv;
            C[(size_t)gr * Fo + gc] = f2b(v);
            ps += v; pq += v * v;
          }
        }
      }
    }
    ps += __shfl_xor(ps, 16); ps += __shfl_xor(ps, 32);
    pq += __shfl_xor(pq, 16); pq += __shfl_xor(pq, 32);
    if (fg == 0 && gc < Fo) {
      int cl = wn * 64 + ni * 16 + fr;
      s2[wm * 128 + cl] = ps;
      s2[256 + wm * 128 + cl] = pq;
    }
  }
  __syncthreads();
  if (tid < 128) {
    int gc = bn0 + tid;
    if (gc < Fo) {
      psum[(size_t)bx * Fo + gc] = s2[tid] + s2[128 + tid];
      psq[(size_t)bx * Fo + gc] = s2[256 + tid] + s2[384 + tid];
    }
  }
}

// ---------------- BN stats ----------------

__global__ void k_colred(const u16* __restrict__ z, int Fo, int n, int rowsPerChunk,
                         float* __restrict__ psum, float* __restrict__ psq) {
  int fl = threadIdx.x & 63;
  int rg = threadIdx.x >> 6;
  int f = blockIdx.y * 64 + fl;
  int r0 = blockIdx.x * rowsPerChunk;
  int r1 = min(n, r0 + rowsPerChunk);
  float s = 0.f, sq = 0.f;
  for (int r = r0 + rg; r < r1; r += 4) {
    float v = b2f(z[(size_t)r * Fo + f]);
    s += v;
    sq += v * v;
  }
  __shared__ float ls[4][64], lq[4][64];
  ls[rg][fl] = s; lq[rg][fl] = sq;
  __syncthreads();
  if (rg == 0) {
    psum[(size_t)blockIdx.x * Fo + f] = ls[0][fl] + ls[1][fl] + ls[2][fl] + ls[3][fl];
    psq[(size_t)blockIdx.x * Fo + f] = lq[0][fl] + lq[1][fl] + lq[2][fl] + lq[3][fl];
  }
}

__global__ void k_bnparams(const float* __restrict__ psum, const float* __restrict__ psq,
                           int Fo, int nChunks, int n,
                           const float* __restrict__ g, const float* __restrict__ bt,
                           float* __restrict__ scaleF, float* __restrict__ shiftF) {
  int f = blockIdx.x * blockDim.x + threadIdx.x;
  if (f >= Fo) return;
  float s = 0.f, sq = 0.f;
  for (int c = 0; c < nChunks; ++c) {
    s += psum[(size_t)c * Fo + f];
    sq += psq[(size_t)c * Fo + f];
  }
  float inv = 1.0f / (float)n;
  float mu = s * inv;
  float var = sq * inv - mu * mu;
  float rs = rsqrtf(var + EPS_BN) * g[f];
  scaleF[f] = rs;
  shiftF[f] = bt[f] - mu * rs;
}

// ---------------- final layer ----------------

__global__ void k_dot512(const u16* __restrict__ z, const float* __restrict__ scaleF,
                         const float* __restrict__ shiftF, const float* __restrict__ w6,
                         const float* __restrict__ dis, float* __restrict__ v, int n) {
  __shared__ float ws[512], scs[512], shs[512];
  int tid = threadIdx.x;
  for (int i = tid; i < 512; i += 256) { ws[i] = w6[i]; scs[i] = scaleF[i]; shs[i] = shiftF[i]; }
  __syncthreads();
  int lane = tid % 64, wv = tid / 64;
  int node = blockIdx.x * 4 + wv;
  if (node >= n) return;
  uint4 vz = *(const uint4*)&z[(size_t)node * 512 + lane * 8];
  float f[8];
  unpack8(vz, f);
  int f0 = lane * 8;
  float s = 0.f;
#pragma unroll
  for (int k = 0; k < 8; ++k) {
    float a = f[k] * scs[f0 + k] + shs[f0 + k];
    a = (a > 0.f) ? a : NEG * a;
    s += a * ws[f0 + k];
  }
#pragma unroll
  for (int off = 32; off > 0; off >>= 1) s += __shfl_down(s, off);
  if (lane == 0) v[node] = dis[node] * s;
}

__global__ void k_final(const float* __restrict__ v, const int* __restrict__ rowoff,
                        const int* __restrict__ col, const float* __restrict__ dis,
                        const float* __restrict__ b6, float* __restrict__ out, int n) {
  int wid = (blockIdx.x * blockDim.x + threadIdx.x) >> 6;
  int lane = threadIdx.x & 63;
  if (wid >= n) return;
  float acc = 0.f;
  int beg = rowoff[wid], end = rowoff[wid + 1];
  for (int e = beg + lane; e < end; e += 64) acc += v[col[e]];
#pragma unroll
  for (int off = 32; off; off >>= 1) acc += __shfl_xor(acc, off);
  if (lane == 0) {
    float zz = dis[wid] * (acc + v[wid]) + b6[0];
    out[wid] = 1.0f / (1.0f + expf(-zz));
  }
}

// ---------------- driver ----------------

extern "C" void kernel_launch(void* const* d_in, const int* in_sizes, int n_in,
                              void* d_out, int out_size, void* d_ws, size_t ws_size,
                              hipStream_t stream) {
  const float* x = (const float*)d_in[0];
  const int* ei = (const int*)d_in[1];
  const int N = in_sizes[0] / 3;
  const int E = in_sizes[1] / 2;
  const int* srcIdx = ei;
  const int* dstIdx = ei + E;

  const float* W[6]; const float* b[6];
  for (int i = 0; i < 6; ++i) { W[i] = (const float*)d_in[2 + 2 * i]; b[i] = (const float*)d_in[3 + 2 * i]; }
  const float* g[5]; const float* bt[5];
  for (int i = 0; i < 5; ++i) { g[i] = (const float*)d_in[14 + 2 * i]; bt[i] = (const float*)d_in[15 + 2 * i]; }

  char* wsB = (char*)d_ws;
  size_t off = 0;
  auto alloc = [&](size_t bytes) -> void* {
    void* p = wsB + off;
    off = (off + bytes + 255) & ~(size_t)255;
    return p;
  };

  const int NB = cdiv(N, 512);            // 196 buckets (<=256)
  int* rowoff = (int*)alloc((size_t)(N + 1) * 4);
  int* col = (int*)alloc((size_t)E * 4);
  float* dis = (float*)alloc((size_t)N * 4);
  float* vbuf = (float*)alloc((size_t)N * 4);
  float* scaleF = (float*)alloc(512 * 4);
  float* shiftF = (float*)alloc(512 * 4);
  u16* WTb = (u16*)alloc((size_t)512 * 256 * 2);
  int* bucketCnt = (int*)alloc(256 * 4);
  int* bucketOff = (int*)alloc(257 * 4);
  int* bucketCur = (int*)alloc(256 * 4);
  const int nbx = cdiv(N, 128);
  float* psum = (float*)alloc((size_t)nbx * 512 * 4);
  float* psq = (float*)alloc((size_t)nbx * 512 * 4);
  u16* Zb = (u16*)alloc((size_t)N * 512 * 2);   // z (and u, in place)
  u16* Ab = (u16*)alloc((size_t)N * 256 * 2);   // aggregated features
  uint2* ebuf = (uint2*)Ab;                     // alias: only used during CSR build

  // ---- CSR build ----
  const int EB = cdiv(E, 4096);
  k_zero_i32<<<1, 256, 0, stream>>>(bucketCnt, 256);
  k_bcount<<<EB, 256, 0, stream>>>(dstIdx, bucketCnt, E);
  k_bscan<<<1, 256, 0, stream>>>(bucketCnt, bucketOff, bucketCur, NB, E);
  k_bucket<<<EB, 256, 0, stream>>>(srcIdx, dstIdx, bucketOff, bucketCur, ebuf, E);
  k_csr<<<NB, 256, 0, stream>>>(ebuf, bucketOff, rowoff, col, dis, N, E, NB);

  auto gemm = [&](const u16* Ain, int layer, int K, int Fo, u16* Cout) {
    k_wt<<<cdiv(K * Fo, 256), 256, 0, stream>>>(W[layer], WTb, K, Fo);
    int nby = cdiv(Fo, 128);
    k_gemm<<<nbx * nby, 256, 0, stream>>>(Ain, WTb, b[layer], Cout, psum, psq, N, K, Fo, nby);
    k_bnparams<<<1, 512, 0, stream>>>(psum, psq, Fo, nbx, N,
                                      g[layer], bt[layer], scaleF, shiftF);
  };

  const int waveGrid = cdiv(N * 64, 256);

  // ---- L1: u1 -> agg(d3) -> gemm(3->64) + colred ----
  k_u1<<<cdiv(N, 256), 256, 0, stream>>>(x, dis, Zb, N);
  k_agg1<<<waveGrid, 256, 0, stream>>>(Zb, rowoff, col, dis, Ab, N);
  k_gemm1<<<cdiv(N, 4), 256, 0, stream>>>(Ab, W[0], b[0], Zb, N);
  {
    const int rowsPerChunk = 2048;
    const int nChunks = cdiv(N, rowsPerChunk);
    dim3 grid(nChunks, 1);
    k_colred<<<grid, 256, 0, stream>>>(Zb, 64, N, rowsPerChunk, psum, psq);
    k_bnparams<<<1, 512, 0, stream>>>(psum, psq, 64, nChunks, N, g[0], bt[0], scaleF, shiftF);
  }

  // ---- L2 ----
  k_u<<<cdiv(N * 8, 256), 256, 0, stream>>>(Zb, scaleF, shiftF, dis, N, 3);
  k_agg64<<<waveGrid, 256, 0, stream>>>(Zb, rowoff, col, dis, Ab, N);
  gemm(Ab, 1, 64, 64, Zb);

  // ---- L3 ----
  k_u<<<cdiv(N * 8, 256), 256, 0, stream>>>(Zb, scaleF, shiftF, dis, N, 3);
  k_agg64<<<waveGrid, 256, 0, stream>>>(Zb, rowoff, col, dis, Ab, N);
  gemm(Ab, 2, 64, 256, Zb);

  // ---- L4 ----
  k_u<<<cdiv(N * 32, 256), 256, 0, stream>>>(Zb, scaleF, shiftF, dis, N, 5);
  k_agg256<<<waveGrid, 256, 0, stream>>>(Zb, rowoff, col, dis, Ab, N);
  gemm(Ab, 3, 256, 256, Zb);

  // ---- L5 ----
  k_u<<<cdiv(N * 32, 256), 256, 0, stream>>>(Zb, scaleF, shiftF, dis, N, 5);
  k_agg256<<<waveGrid, 256, 0, stream>>>(Zb, rowoff, col, dis, Ab, N);
  gemm(Ab, 4, 256, 512, Zb);

  // ---- L6 ----
  k_dot512<<<cdiv(N, 4), 256, 0, stream>>>(Zb, scaleF, shiftF, W[5], dis, vbuf, N);
  k_final<<<waveGrid, 256, 0, stream>>>(vbuf, rowoff, col, dis, b[5], (float*)d_out, N);
}

// Round 5
// 1245.590 us; speedup vs baseline: 2.1685x; 1.6786x over previous
//
#include <hip/hip_runtime.h>
#include <math.h>

typedef unsigned short u16;
typedef unsigned int u32;
typedef __attribute__((ext_vector_type(8))) short bf16x8;
typedef __attribute__((ext_vector_type(4))) float f32x4;

constexpr float EPS_BN = 1e-5f;
constexpr float NEG = 0.1f;
constexpr int LDP = 800;   // leading dim of psum/psq: [feature][chunk<=LDP]

static inline int cdiv(int a, int b) { return (a + b - 1) / b; }

// ---------------- bf16 helpers ----------------

__device__ __forceinline__ float b2f_lo(u32 v) { return __uint_as_float(v << 16); }
__device__ __forceinline__ float b2f_hi(u32 v) { return __uint_as_float(v & 0xFFFF0000u); }
__device__ __forceinline__ float b2f(u16 v) { return __uint_as_float(((u32)v) << 16); }
__device__ __forceinline__ u16 f2b(float f) {
  u32 u = __float_as_uint(f);
  u32 r = u + 0x7FFFu + ((u >> 16) & 1u);
  return (u16)(r >> 16);
}
__device__ __forceinline__ u32 pack2(float a, float b) {
  return (u32)f2b(a) | ((u32)f2b(b) << 16);
}
__device__ __forceinline__ void unpack8(uint4 v, float* o) {
  o[0] = b2f_lo(v.x); o[1] = b2f_hi(v.x);
  o[2] = b2f_lo(v.y); o[3] = b2f_hi(v.y);
  o[4] = b2f_lo(v.z); o[5] = b2f_hi(v.z);
  o[6] = b2f_lo(v.w); o[7] = b2f_hi(v.w);
}
__device__ __forceinline__ void unpack4(uint2 v, float* o) {
  o[0] = b2f_lo(v.x); o[1] = b2f_hi(v.x);
  o[2] = b2f_lo(v.y); o[3] = b2f_hi(v.y);
}

// ---------------- CSR build (bucketed, low write-amplification) ----------------

__global__ void k_zero_i32(int* p, int n) {
  int i = blockIdx.x * blockDim.x + threadIdx.x;
  if (i < n) p[i] = 0;
}

__global__ __launch_bounds__(256) void k_bcount(const int* __restrict__ dst,
                                                int* __restrict__ bucketCnt, int E) {
  __shared__ int hist[256];
  int tid = threadIdx.x;
  hist[tid] = 0;
  __syncthreads();
  int e0 = blockIdx.x * 4096;
#pragma unroll
  for (int i = 0; i < 16; ++i) {
    int e = e0 + i * 256 + tid;
    if (e < E) atomicAdd(&hist[dst[e] >> 9], 1);
  }
  __syncthreads();
  int h = hist[tid];
  if (h > 0) atomicAdd(&bucketCnt[tid], h);
}

__global__ void k_bscan(const int* __restrict__ bucketCnt, int* __restrict__ bucketOff,
                        int* __restrict__ bucketCur, int NB, int E) {
  __shared__ int s[256];
  int tid = threadIdx.x;
  int v = (tid < NB) ? bucketCnt[tid] : 0;
  s[tid] = v;
  __syncthreads();
  for (int off = 1; off < 256; off <<= 1) {
    int t = (tid >= off) ? s[tid - off] : 0;
    __syncthreads();
    s[tid] += t;
    __syncthreads();
  }
  if (tid < NB) bucketOff[tid] = s[tid] - v;
  if (tid == NB) bucketOff[NB] = E;
  if (tid < NB) bucketCur[tid] = 0;
}

__global__ __launch_bounds__(256) void k_bucket(const int* __restrict__ src,
                                                const int* __restrict__ dst,
                                                const int* __restrict__ bucketOff,
                                                int* __restrict__ bucketCur,
                                                uint2* __restrict__ ebuf, int E) {
  __shared__ int hist[256];
  __shared__ int base[256];
  __shared__ int lcur[256];
  int tid = threadIdx.x;
  hist[tid] = 0; lcur[tid] = 0;
  __syncthreads();
  int e0 = blockIdx.x * 4096;
  int ss[16], dd[16];
#pragma unroll
  for (int i = 0; i < 16; ++i) {
    int e = e0 + i * 256 + tid;
    if (e < E) {
      ss[i] = src[e]; dd[i] = dst[e];
      atomicAdd(&hist[dd[i] >> 9], 1);
    } else dd[i] = -1;
  }
  __syncthreads();
  int h = hist[tid];
  if (h > 0) base[tid] = bucketOff[tid] + atomicAdd(&bucketCur[tid], h);
  __syncthreads();
#pragma unroll
  for (int i = 0; i < 16; ++i) {
    if (dd[i] >= 0) {
      int bk = dd[i] >> 9;
      int p = atomicAdd(&lcur[bk], 1);
      ebuf[base[bk] + p] = make_uint2((u32)ss[i], (u32)dd[i]);
    }
  }
}

__global__ __launch_bounds__(256) void k_csr(const uint2* __restrict__ ebuf,
                                             const int* __restrict__ bucketOff,
                                             int* __restrict__ rowoff,
                                             int* __restrict__ col,
                                             float* __restrict__ dis,
                                             int N, int E, int NB) {
  __shared__ int hist[512];
  __shared__ int loff[512];
  __shared__ int scan_s[256];
  int b = blockIdx.x;
  int tid = threadIdx.x;
  int ebase = bucketOff[b], eend = bucketOff[b + 1];
  int ecnt = eend - ebase;
  hist[tid] = 0; hist[tid + 256] = 0;
  __syncthreads();
  for (int i = tid; i < ecnt; i += 256)
    atomicAdd(&hist[ebuf[ebase + i].y & 511], 1);
  __syncthreads();
  int h0 = hist[2 * tid], h1 = hist[2 * tid + 1];
  int ts = h0 + h1;
  scan_s[tid] = ts;
  __syncthreads();
  for (int off = 1; off < 256; off <<= 1) {
    int t = (tid >= off) ? scan_s[tid - off] : 0;
    __syncthreads();
    scan_s[tid] += t;
    __syncthreads();
  }
  int excl = scan_s[tid] - ts;
  loff[2 * tid] = excl;
  loff[2 * tid + 1] = excl + h0;
  __syncthreads();
  int gbase = b * 512;
  for (int i = tid; i < 512; i += 256) {
    int node = gbase + i;
    if (node < N) {
      rowoff[node] = ebase + loff[i];
      dis[node] = rsqrtf((float)hist[i] + 1.0f);
    }
  }
  if (b == NB - 1 && tid == 0) rowoff[N] = E;
  __syncthreads();
  for (int i = tid; i < ecnt; i += 256) {
    uint2 ed = ebuf[ebase + i];
    int p = atomicAdd(&loff[ed.y & 511], 1);
    col[ebase + p] = (int)ed.x;
  }
}

// ---------------- L1 pieces ----------------

__global__ void k_u1(const float* __restrict__ x, const float* __restrict__ dis,
                     u16* __restrict__ u, int n) {
  int i = blockIdx.x * blockDim.x + threadIdx.x;
  if (i >= n) return;
  float d = dis[i];
  u32 p0 = pack2(d * x[i * 3 + 0], d * x[i * 3 + 1]);
  u32 p1 = pack2(d * x[i * 3 + 2], 0.0f);
  ((uint2*)u)[i] = make_uint2(p0, p1);
}

__global__ void k_agg1(const u16* __restrict__ u, const int* __restrict__ rowoff,
                       const int* __restrict__ col, const float* __restrict__ dis,
                       u16* __restrict__ a, int n) {
  int wid = (blockIdx.x * blockDim.x + threadIdx.x) >> 6;
  int lane = threadIdx.x & 63;
  if (wid >= n) return;
  const uint2* u2 = (const uint2*)u;
  float a0 = 0.f, a1 = 0.f, a2 = 0.f;
  int beg = rowoff[wid], end = rowoff[wid + 1];
  for (int e = beg + lane; e < end; e += 64) {
    uint2 w = u2[col[e]];
    a0 += b2f_lo(w.x); a1 += b2f_hi(w.x); a2 += b2f_lo(w.y);
  }
#pragma unroll
  for (int off = 32; off; off >>= 1) {
    a0 += __shfl_xor(a0, off); a1 += __shfl_xor(a1, off); a2 += __shfl_xor(a2, off);
  }
  if (lane == 0) {
    uint2 s = u2[wid];
    a0 += b2f_lo(s.x); a1 += b2f_hi(s.x); a2 += b2f_lo(s.y);
    float d = dis[wid];
    ((uint2*)a)[wid] = make_uint2(pack2(d * a0, d * a1), pack2(d * a2, 0.0f));
  }
}

__global__ void k_gemm1(const u16* __restrict__ a, const float* __restrict__ W,
                        const float* __restrict__ b, u16* __restrict__ z, int n) {
  __shared__ float Ws[3][64];
  __shared__ float bs[64];
  int tid = threadIdx.x;
  if (tid < 192) Ws[tid / 64][tid % 64] = W[tid];
  if (tid < 64) bs[tid] = b[tid];
  __syncthreads();
  int f = tid % 64, r = tid / 64;
  int node = blockIdx.x * 4 + r;
  if (node >= n) return;
  uint2 v = ((const uint2*)a)[node];
  float a0 = b2f_lo(v.x), a1 = b2f_hi(v.x), a2 = b2f_lo(v.y);
  float zv = a0 * Ws[0][f] + a1 * Ws[1][f] + a2 * Ws[2][f] + bs[f];
  z[(size_t)node * 64 + f] = f2b(zv);
}

// ---------------- aggregations ----------------

__global__ void k_agg64(const u16* __restrict__ u, const int* __restrict__ rowoff,
                        const int* __restrict__ col, const float* __restrict__ dis,
                        u16* __restrict__ a, int n) {
  int wid = (blockIdx.x * blockDim.x + threadIdx.x) >> 6;
  int lane = threadIdx.x & 63;
  if (wid >= n) return;
  int sub = lane >> 4, c = lane & 15;
  const uint2* u2 = (const uint2*)u;
  float acc[4] = {0.f, 0.f, 0.f, 0.f};
  if (sub == 0) {
    float s[4]; unpack4(u2[(size_t)wid * 16 + c], s);
#pragma unroll
    for (int k = 0; k < 4; ++k) acc[k] = s[k];
  }
  int beg = rowoff[wid], end = rowoff[wid + 1];
  int e = beg + sub;
  for (; e + 4 < end; e += 8) {
    int j1 = col[e], j2 = col[e + 4];
    uint2 v1 = u2[(size_t)j1 * 16 + c];
    uint2 v2 = u2[(size_t)j2 * 16 + c];
    float f1[4], f2[4];
    unpack4(v1, f1); unpack4(v2, f2);
#pragma unroll
    for (int k = 0; k < 4; ++k) acc[k] += f1[k] + f2[k];
  }
  if (e < end) {
    float f1[4]; unpack4(u2[(size_t)col[e] * 16 + c], f1);
#pragma unroll
    for (int k = 0; k < 4; ++k) acc[k] += f1[k];
  }
#pragma unroll
  for (int k = 0; k < 4; ++k) {
    acc[k] += __shfl_xor(acc[k], 16);
    acc[k] += __shfl_xor(acc[k], 32);
  }
  if (sub == 0) {
    float d = dis[wid];
    ((uint2*)a)[(size_t)wid * 16 + c] =
        make_uint2(pack2(d * acc[0], d * acc[1]), pack2(d * acc[2], d * acc[3]));
  }
}

__global__ void k_agg256(const u16* __restrict__ u, const int* __restrict__ rowoff,
                         const int* __restrict__ col, const float* __restrict__ dis,
                         u16* __restrict__ a, int n) {
  int wid = (blockIdx.x * blockDim.x + threadIdx.x) >> 6;
  int lane = threadIdx.x & 63;
  if (wid >= n) return;
  int sub = lane >> 5, c = lane & 31;
  const uint4* u4 = (const uint4*)u;
  float acc[8] = {0.f, 0.f, 0.f, 0.f, 0.f, 0.f, 0.f, 0.f};
  if (sub == 0) {
    float s[8]; unpack8(u4[(size_t)wid * 32 + c], s);
#pragma unroll
    for (int k = 0; k < 8; ++k) acc[k] = s[k];
  }
  int beg = rowoff[wid], end = rowoff[wid + 1];
  int e = beg + sub;
  for (; e + 2 < end; e += 4) {
    int j1 = col[e], j2 = col[e + 2];
    uint4 v1 = u4[(size_t)j1 * 32 + c];
    uint4 v2 = u4[(size_t)j2 * 32 + c];
    float f1[8], f2[8];
    unpack8(v1, f1); unpack8(v2, f2);
#pragma unroll
    for (int k = 0; k < 8; ++k) acc[k] += f1[k] + f2[k];
  }
  if (e < end) {
    float f1[8]; unpack8(u4[(size_t)col[e] * 32 + c], f1);
#pragma unroll
    for (int k = 0; k < 8; ++k) acc[k] += f1[k];
  }
#pragma unroll
  for (int k = 0; k < 8; ++k) acc[k] += __shfl_xor(acc[k], 32);
  if (sub == 0) {
    float d = dis[wid];
    uint4 r;
    r.x = pack2(d * acc[0], d * acc[1]);
    r.y = pack2(d * acc[2], d * acc[3]);
    r.z = pack2(d * acc[4], d * acc[5]);
    r.w = pack2(d * acc[6], d * acc[7]);
    ((uint4*)a)[(size_t)wid * 32 + c] = r;
  }
}

// ---------------- BN fold (in-place) ----------------

__global__ void k_u(u16* __restrict__ z, const float* __restrict__ scaleF,
                    const float* __restrict__ shiftF, const float* __restrict__ dis,
                    int n, int lg) {
  size_t idx = (size_t)blockIdx.x * blockDim.x + threadIdx.x;
  size_t tot = ((size_t)n) << lg;
  if (idx >= tot) return;
  int g = (int)(idx & ((1u << lg) - 1));
  int node = (int)(idx >> lg);
  uint4 v = ((const uint4*)z)[idx];
  float f[8];
  unpack8(v, f);
  int f0 = g * 8;
  float4 s0 = *(const float4*)&scaleF[f0];
  float4 s1 = *(const float4*)&scaleF[f0 + 4];
  float4 h0 = *(const float4*)&shiftF[f0];
  float4 h1 = *(const float4*)&shiftF[f0 + 4];
  float d = dis[node];
  float o[8];
  o[0] = f[0] * s0.x + h0.x; o[1] = f[1] * s0.y + h0.y;
  o[2] = f[2] * s0.z + h0.z; o[3] = f[3] * s0.w + h0.w;
  o[4] = f[4] * s1.x + h1.x; o[5] = f[5] * s1.y + h1.y;
  o[6] = f[6] * s1.z + h1.z; o[7] = f[7] * s1.w + h1.w;
#pragma unroll
  for (int k = 0; k < 8; ++k) {
    float a = o[k];
    a = (a > 0.f) ? a : NEG * a;
    o[k] = d * a;
  }
  uint4 r;
  r.x = pack2(o[0], o[1]); r.y = pack2(o[2], o[3]);
  r.z = pack2(o[4], o[5]); r.w = pack2(o[6], o[7]);
  ((uint4*)z)[idx] = r;
}

// ---------------- MFMA GEMM with fused column stats ----------------

__global__ void k_wt(const float* __restrict__ W, u16* __restrict__ WT, int K, int Fo) {
  int i = blockIdx.x * blockDim.x + threadIdx.x;
  if (i >= K * Fo) return;
  int f = i / K, k = i - f * K;
  WT[i] = f2b(W[(size_t)k * Fo + f]);
}

// C[n,Fo](bf16) = A[n,K](bf16) @ WT[Fo,K]^T + bias ; psum/psq[col][bx] (LDP)
__global__ __launch_bounds__(256) void k_gemm(const u16* __restrict__ A,
                                              const u16* __restrict__ WT,
                                              const float* __restrict__ bias,
                                              u16* __restrict__ C,
                                              float* __restrict__ psum,
                                              float* __restrict__ psq,
                                              int n, int K, int Fo, int nby) {
  __shared__ u16 As[128][72];
  __shared__ u16 Bs[128][72];
  int tid = threadIdx.x;
  int nwg = gridDim.x;
  int bid = blockIdx.x;
  int q = nwg >> 3, rr = nwg & 7;
  int xcd = bid & 7, pos = bid >> 3;
  int wgid = (xcd < rr ? xcd * (q + 1) : rr * (q + 1) + (xcd - rr) * q) + pos;
  int bx = wgid / nby, by = wgid - bx * nby;
  int bm0 = bx * 128, bn0 = by * 128;
  int lane = tid & 63, wid = tid >> 6;
  int wm = wid >> 1, wn = wid & 1;
  int lr = tid & 127;
  int lh = (tid >> 7) * 32;
  int fr = lane & 15, fg = lane >> 4;
  f32x4 acc[4][4];
#pragma unroll
  for (int i = 0; i < 4; ++i)
#pragma unroll
    for (int j = 0; j < 4; ++j) acc[i][j] = (f32x4)0.0f;

  for (int kt = 0; kt < K; kt += 64) {
    {
      int row = bm0 + lr;
      uint4 v[4];
#pragma unroll
      for (int i = 0; i < 4; ++i) {
        v[i] = make_uint4(0u, 0u, 0u, 0u);
        if (row < n) v[i] = *(const uint4*)&A[(size_t)row * K + kt + lh + i * 8];
      }
      int fo = bn0 + lr;
      uint4 w[4];
#pragma unroll
      for (int i = 0; i < 4; ++i) {
        w[i] = make_uint4(0u, 0u, 0u, 0u);
        if (fo < Fo) w[i] = *(const uint4*)&WT[(size_t)fo * K + kt + lh + i * 8];
      }
#pragma unroll
      for (int i = 0; i < 4; ++i) *(uint4*)&As[lr][lh + i * 8] = v[i];
#pragma unroll
      for (int i = 0; i < 4; ++i) *(uint4*)&Bs[lr][lh + i * 8] = w[i];
    }
    __syncthreads();
#pragma unroll
    for (int ks = 0; ks < 2; ++ks) {
      int k0 = ks * 32 + fg * 8;
      bf16x8 af[4], bf[4];
#pragma unroll
      for (int mi = 0; mi < 4; ++mi) af[mi] = *(const bf16x8*)&As[wm * 64 + mi * 16 + fr][k0];
#pragma unroll
      for (int ni = 0; ni < 4; ++ni) bf[ni] = *(const bf16x8*)&Bs[wn * 64 + ni * 16 + fr][k0];
#pragma unroll
      for (int mi = 0; mi < 4; ++mi)
#pragma unroll
        for (int ni = 0; ni < 4; ++ni)
          acc[mi][ni] = __builtin_amdgcn_mfma_f32_16x16x32_bf16(af[mi], bf[ni], acc[mi][ni], 0, 0, 0);
    }
    __syncthreads();
  }
  // epilogue: C-write + per-block column sum/sumsq (LDS aliased over As)
  float* s2 = (float*)&As[0][0];
#pragma unroll
  for (int ni = 0; ni < 4; ++ni) {
    int gc = bn0 + wn * 64 + ni * 16 + fr;
    float ps = 0.f, pq = 0.f;
    if (gc < Fo) {
      float bv = bias[gc];
#pragma unroll
      for (int mi = 0; mi < 4; ++mi) {
#pragma unroll
        for (int rg = 0; rg < 4; ++rg) {
          int gr = bm0 + wm * 64 + mi * 16 + fg * 4 + rg;
          if (gr < n) {
            float v = acc[mi][ni][rg] + bv;
            C[(size_t)gr * Fo + gc] = f2b(v);
            ps += v; pq += v * v;
          }
        }
      }
    }
    ps += __shfl_xor(ps, 16); ps += __shfl_xor(ps, 32);
    pq += __shfl_xor(pq, 16); pq += __shfl_xor(pq, 32);
    if (fg == 0 && gc < Fo) {
      int cl = wn * 64 + ni * 16 + fr;
      s2[wm * 128 + cl] = ps;
      s2[256 + wm * 128 + cl] = pq;
    }
  }
  __syncthreads();
  if (tid < 128) {
    int gc = bn0 + tid;
    if (gc < Fo) {
      psum[(size_t)gc * LDP + bx] = s2[tid] + s2[128 + tid];
      psq[(size_t)gc * LDP + bx] = s2[256 + tid] + s2[384 + tid];
    }
  }
}

// ---------------- BN stats ----------------

// transposed write: psum[f][chunk]
__global__ void k_colred(const u16* __restrict__ z, int Fo, int n, int rowsPerChunk,
                         float* __restrict__ psum, float* __restrict__ psq) {
  int fl = threadIdx.x & 63;
  int rg = threadIdx.x >> 6;
  int f = blockIdx.y * 64 + fl;
  int r0 = blockIdx.x * rowsPerChunk;
  int r1 = min(n, r0 + rowsPerChunk);
  float s = 0.f, sq = 0.f;
  for (int r = r0 + rg; r < r1; r += 4) {
    float v = b2f(z[(size_t)r * Fo + f]);
    s += v;
    sq += v * v;
  }
  __shared__ float ls[4][64], lq[4][64];
  ls[rg][fl] = s; lq[rg][fl] = sq;
  __syncthreads();
  if (rg == 0) {
    psum[(size_t)f * LDP + blockIdx.x] = ls[0][fl] + ls[1][fl] + ls[2][fl] + ls[3][fl];
    psq[(size_t)f * LDP + blockIdx.x] = lq[0][fl] + lq[1][fl] + lq[2][fl] + lq[3][fl];
  }
}

// one wave per feature; lane-strided coalesced chunk reads, shfl tree reduce
__global__ void k_bnparams(const float* __restrict__ psum, const float* __restrict__ psq,
                           int Fo, int nChunks, int n,
                           const float* __restrict__ g, const float* __restrict__ bt,
                           float* __restrict__ scaleF, float* __restrict__ shiftF) {
  int f = blockIdx.x * 4 + (threadIdx.x >> 6);
  int lane = threadIdx.x & 63;
  if (f >= Fo) return;
  float s = 0.f, sq = 0.f;
  const float* ps = &psum[(size_t)f * LDP];
  const float* pq = &psq[(size_t)f * LDP];
  for (int c = lane; c < nChunks; c += 64) { s += ps[c]; sq += pq[c]; }
#pragma unroll
  for (int off = 32; off; off >>= 1) {
    s += __shfl_xor(s, off);
    sq += __shfl_xor(sq, off);
  }
  if (lane == 0) {
    float inv = 1.0f / (float)n;
    float mu = s * inv;
    float var = sq * inv - mu * mu;
    float rs = rsqrtf(var + EPS_BN) * g[f];
    scaleF[f] = rs;
    shiftF[f] = bt[f] - mu * rs;
  }
}

// ---------------- final layer ----------------

__global__ void k_dot512(const u16* __restrict__ z, const float* __restrict__ scaleF,
                         const float* __restrict__ shiftF, const float* __restrict__ w6,
                         const float* __restrict__ dis, float* __restrict__ v, int n) {
  __shared__ float ws[512], scs[512], shs[512];
  int tid = threadIdx.x;
  for (int i = tid; i < 512; i += 256) { ws[i] = w6[i]; scs[i] = scaleF[i]; shs[i] = shiftF[i]; }
  __syncthreads();
  int lane = tid % 64, wv = tid / 64;
  int node = blockIdx.x * 4 + wv;
  if (node >= n) return;
  uint4 vz = *(const uint4*)&z[(size_t)node * 512 + lane * 8];
  float f[8];
  unpack8(vz, f);
  int f0 = lane * 8;
  float s = 0.f;
#pragma unroll
  for (int k = 0; k < 8; ++k) {
    float a = f[k] * scs[f0 + k] + shs[f0 + k];
    a = (a > 0.f) ? a : NEG * a;
    s += a * ws[f0 + k];
  }
#pragma unroll
  for (int off = 32; off > 0; off >>= 1) s += __shfl_down(s, off);
  if (lane == 0) v[node] = dis[node] * s;
}

__global__ void k_final(const float* __restrict__ v, const int* __restrict__ rowoff,
                        const int* __restrict__ col, const float* __restrict__ dis,
                        const float* __restrict__ b6, float* __restrict__ out, int n) {
  int wid = (blockIdx.x * blockDim.x + threadIdx.x) >> 6;
  int lane = threadIdx.x & 63;
  if (wid >= n) return;
  float acc = 0.f;
  int beg = rowoff[wid], end = rowoff[wid + 1];
  for (int e = beg + lane; e < end; e += 64) acc += v[col[e]];
#pragma unroll
  for (int off = 32; off; off >>= 1) acc += __shfl_xor(acc, off);
  if (lane == 0) {
    float zz = dis[wid] * (acc + v[wid]) + b6[0];
    out[wid] = 1.0f / (1.0f + expf(-zz));
  }
}

// ---------------- driver ----------------

extern "C" void kernel_launch(void* const* d_in, const int* in_sizes, int n_in,
                              void* d_out, int out_size, void* d_ws, size_t ws_size,
                              hipStream_t stream) {
  const float* x = (const float*)d_in[0];
  const int* ei = (const int*)d_in[1];
  const int N = in_sizes[0] / 3;
  const int E = in_sizes[1] / 2;
  const int* srcIdx = ei;
  const int* dstIdx = ei + E;

  const float* W[6]; const float* b[6];
  for (int i = 0; i < 6; ++i) { W[i] = (const float*)d_in[2 + 2 * i]; b[i] = (const float*)d_in[3 + 2 * i]; }
  const float* g[5]; const float* bt[5];
  for (int i = 0; i < 5; ++i) { g[i] = (const float*)d_in[14 + 2 * i]; bt[i] = (const float*)d_in[15 + 2 * i]; }

  char* wsB = (char*)d_ws;
  size_t off = 0;
  auto alloc = [&](size_t bytes) -> void* {
    void* p = wsB + off;
    off = (off + bytes + 255) & ~(size_t)255;
    return p;
  };

  const int NB = cdiv(N, 512);
  int* rowoff = (int*)alloc((size_t)(N + 1) * 4);
  int* col = (int*)alloc((size_t)E * 4);
  float* dis = (float*)alloc((size_t)N * 4);
  float* vbuf = (float*)alloc((size_t)N * 4);
  float* scaleF = (float*)alloc(512 * 4);
  float* shiftF = (float*)alloc(512 * 4);
  u16* WTb = (u16*)alloc((size_t)512 * 256 * 2);
  int* bucketCnt = (int*)alloc(256 * 4);
  int* bucketOff = (int*)alloc(257 * 4);
  int* bucketCur = (int*)alloc(256 * 4);
  const int nbx = cdiv(N, 128);
  float* psum = (float*)alloc((size_t)512 * LDP * 4);
  float* psq = (float*)alloc((size_t)512 * LDP * 4);
  u16* Zb = (u16*)alloc((size_t)N * 512 * 2);
  u16* Ab = (u16*)alloc((size_t)N * 256 * 2);
  uint2* ebuf = (uint2*)Ab;

  // ---- CSR build ----
  const int EB = cdiv(E, 4096);
  k_zero_i32<<<1, 256, 0, stream>>>(bucketCnt, 256);
  k_bcount<<<EB, 256, 0, stream>>>(dstIdx, bucketCnt, E);
  k_bscan<<<1, 256, 0, stream>>>(bucketCnt, bucketOff, bucketCur, NB, E);
  k_bucket<<<EB, 256, 0, stream>>>(srcIdx, dstIdx, bucketOff, bucketCur, ebuf, E);
  k_csr<<<NB, 256, 0, stream>>>(ebuf, bucketOff, rowoff, col, dis, N, E, NB);

  auto gemm = [&](const u16* Ain, int layer, int K, int Fo, u16* Cout) {
    k_wt<<<cdiv(K * Fo, 256), 256, 0, stream>>>(W[layer], WTb, K, Fo);
    int nby = cdiv(Fo, 128);
    k_gemm<<<nbx * nby, 256, 0, stream>>>(Ain, WTb, b[layer], Cout, psum, psq, N, K, Fo, nby);
    k_bnparams<<<cdiv(Fo, 4), 256, 0, stream>>>(psum, psq, Fo, nbx, N,
                                                g[layer], bt[layer], scaleF, shiftF);
  };

  const int waveGrid = cdiv(N * 64, 256);

  // ---- L1 ----
  k_u1<<<cdiv(N, 256), 256, 0, stream>>>(x, dis, Zb, N);
  k_agg1<<<waveGrid, 256, 0, stream>>>(Zb, rowoff, col, dis, Ab, N);
  k_gemm1<<<cdiv(N, 4), 256, 0, stream>>>(Ab, W[0], b[0], Zb, N);
  {
    const int rowsPerChunk = 2048;
    const int nChunks = cdiv(N, rowsPerChunk);
    dim3 grid(nChunks, 1);
    k_colred<<<grid, 256, 0, stream>>>(Zb, 64, N, rowsPerChunk, psum, psq);
    k_bnparams<<<cdiv(64, 4), 256, 0, stream>>>(psum, psq, 64, nChunks, N, g[0], bt[0], scaleF, shiftF);
  }

  // ---- L2 ----
  k_u<<<cdiv(N * 8, 256), 256, 0, stream>>>(Zb, scaleF, shiftF, dis, N, 3);
  k_agg64<<<waveGrid, 256, 0, stream>>>(Zb, rowoff, col, dis, Ab, N);
  gemm(Ab, 1, 64, 64, Zb);

  // ---- L3 ----
  k_u<<<cdiv(N * 8, 256), 256, 0, stream>>>(Zb, scaleF, shiftF, dis, N, 3);
  k_agg64<<<waveGrid, 256, 0, stream>>>(Zb, rowoff, col, dis, Ab, N);
  gemm(Ab, 2, 64, 256, Zb);

  // ---- L4 ----
  k_u<<<cdiv(N * 32, 256), 256, 0, stream>>>(Zb, scaleF, shiftF, dis, N, 5);
  k_agg256<<<waveGrid, 256, 0, stream>>>(Zb, rowoff, col, dis, Ab, N);
  gemm(Ab, 3, 256, 256, Zb);

  // ---- L5 ----
  k_u<<<cdiv(N * 32, 256), 256, 0, stream>>>(Zb, scaleF, shiftF, dis, N, 5);
  k_agg256<<<waveGrid, 256, 0, stream>>>(Zb, rowoff, col, dis, Ab, N);
  gemm(Ab, 4, 256, 512, Zb);

  // ---- L6 ----
  k_dot512<<<cdiv(N, 4), 256, 0, stream>>>(Zb, scaleF, shiftF, W[5], dis, vbuf, N);
  k_final<<<waveGrid, 256, 0, stream>>>(vbuf, rowoff, col, dis, b[5], (float*)d_out, N);
}

// Round 6
// 1235.267 us; speedup vs baseline: 2.1866x; 1.0084x over previous
//
#include <hip/hip_runtime.h>
#include <math.h>

typedef unsigned short u16;
typedef unsigned int u32;
typedef __attribute__((ext_vector_type(8))) short bf16x8;
typedef __attribute__((ext_vector_type(4))) float f32x4;

constexpr float EPS_BN = 1e-5f;
constexpr float NEG = 0.1f;
constexpr int LDP = 800;   // leading dim of psum/psq: [feature][chunk<=LDP]

static inline int cdiv(int a, int b) { return (a + b - 1) / b; }

// ---------------- bf16 helpers ----------------

__device__ __forceinline__ float b2f_lo(u32 v) { return __uint_as_float(v << 16); }
__device__ __forceinline__ float b2f_hi(u32 v) { return __uint_as_float(v & 0xFFFF0000u); }
__device__ __forceinline__ float b2f(u16 v) { return __uint_as_float(((u32)v) << 16); }
__device__ __forceinline__ u16 f2b(float f) {
  u32 u = __float_as_uint(f);
  u32 r = u + 0x7FFFu + ((u >> 16) & 1u);
  return (u16)(r >> 16);
}
__device__ __forceinline__ u32 pack2(float a, float b) {
  return (u32)f2b(a) | ((u32)f2b(b) << 16);
}
__device__ __forceinline__ void unpack8(uint4 v, float* o) {
  o[0] = b2f_lo(v.x); o[1] = b2f_hi(v.x);
  o[2] = b2f_lo(v.y); o[3] = b2f_hi(v.y);
  o[4] = b2f_lo(v.z); o[5] = b2f_hi(v.z);
  o[6] = b2f_lo(v.w); o[7] = b2f_hi(v.w);
}
__device__ __forceinline__ void unpack4(uint2 v, float* o) {
  o[0] = b2f_lo(v.x); o[1] = b2f_hi(v.x);
  o[2] = b2f_lo(v.y); o[3] = b2f_hi(v.y);
}

// ---------------- CSR build (bucketed, packed ebuf) ----------------

__global__ void k_zero_i32(int* p, int n) {
  int i = blockIdx.x * blockDim.x + threadIdx.x;
  if (i < n) p[i] = 0;
}

__global__ __launch_bounds__(256) void k_bcount(const int* __restrict__ dst,
                                                int* __restrict__ bucketCnt, int E) {
  __shared__ int hist[256];
  int tid = threadIdx.x;
  hist[tid] = 0;
  __syncthreads();
  int e0 = blockIdx.x * 4096;
#pragma unroll
  for (int i = 0; i < 16; ++i) {
    int e = e0 + i * 256 + tid;
    if (e < E) atomicAdd(&hist[dst[e] >> 9], 1);
  }
  __syncthreads();
  int h = hist[tid];
  if (h > 0) atomicAdd(&bucketCnt[tid], h);
}

__global__ void k_bscan(const int* __restrict__ bucketCnt, int* __restrict__ bucketOff,
                        int* __restrict__ bucketCur, int NB, int E) {
  __shared__ int s[256];
  int tid = threadIdx.x;
  int v = (tid < NB) ? bucketCnt[tid] : 0;
  s[tid] = v;
  __syncthreads();
  for (int off = 1; off < 256; off <<= 1) {
    int t = (tid >= off) ? s[tid - off] : 0;
    __syncthreads();
    s[tid] += t;
    __syncthreads();
  }
  if (tid < NB) bucketOff[tid] = s[tid] - v;
  if (tid == NB) bucketOff[NB] = E;
  if (tid < NB) bucketCur[tid] = 0;
}

// scatter packed (src<<9 | dst&511) into bucket regions
__global__ __launch_bounds__(256) void k_bucket(const int* __restrict__ src,
                                                const int* __restrict__ dst,
                                                const int* __restrict__ bucketOff,
                                                int* __restrict__ bucketCur,
                                                u32* __restrict__ ebuf, int E) {
  __shared__ int hist[256];
  __shared__ int base[256];
  __shared__ int lcur[256];
  int tid = threadIdx.x;
  hist[tid] = 0; lcur[tid] = 0;
  __syncthreads();
  int e0 = blockIdx.x * 4096;
  int ss[16], dd[16];
#pragma unroll
  for (int i = 0; i < 16; ++i) {
    int e = e0 + i * 256 + tid;
    if (e < E) {
      ss[i] = src[e]; dd[i] = dst[e];
      atomicAdd(&hist[dd[i] >> 9], 1);
    } else dd[i] = -1;
  }
  __syncthreads();
  int h = hist[tid];
  if (h > 0) base[tid] = bucketOff[tid] + atomicAdd(&bucketCur[tid], h);
  __syncthreads();
#pragma unroll
  for (int i = 0; i < 16; ++i) {
    if (dd[i] >= 0) {
      int bk = dd[i] >> 9;
      int p = atomicAdd(&lcur[bk], 1);
      ebuf[base[bk] + p] = ((u32)ss[i] << 9) | ((u32)dd[i] & 511u);
    }
  }
}

__global__ __launch_bounds__(256) void k_csr(const u32* __restrict__ ebuf,
                                             const int* __restrict__ bucketOff,
                                             int* __restrict__ rowoff,
                                             int* __restrict__ col,
                                             float* __restrict__ dis,
                                             int N, int E, int NB) {
  __shared__ int hist[512];
  __shared__ int loff[512];
  __shared__ int scan_s[256];
  int b = blockIdx.x;
  int tid = threadIdx.x;
  int ebase = bucketOff[b], eend = bucketOff[b + 1];
  int ecnt = eend - ebase;
  hist[tid] = 0; hist[tid + 256] = 0;
  __syncthreads();
  for (int i = tid; i < ecnt; i += 256)
    atomicAdd(&hist[ebuf[ebase + i] & 511u], 1);
  __syncthreads();
  int h0 = hist[2 * tid], h1 = hist[2 * tid + 1];
  int ts = h0 + h1;
  scan_s[tid] = ts;
  __syncthreads();
  for (int off = 1; off < 256; off <<= 1) {
    int t = (tid >= off) ? scan_s[tid - off] : 0;
    __syncthreads();
    scan_s[tid] += t;
    __syncthreads();
  }
  int excl = scan_s[tid] - ts;
  loff[2 * tid] = excl;
  loff[2 * tid + 1] = excl + h0;
  __syncthreads();
  int gbase = b * 512;
  for (int i = tid; i < 512; i += 256) {
    int node = gbase + i;
    if (node < N) {
      rowoff[node] = ebase + loff[i];
      dis[node] = rsqrtf((float)hist[i] + 1.0f);
    }
  }
  if (b == NB - 1 && tid == 0) rowoff[N] = E;
  __syncthreads();
  for (int i = tid; i < ecnt; i += 256) {
    u32 ed = ebuf[ebase + i];
    int p = atomicAdd(&loff[ed & 511u], 1);
    col[ebase + p] = (int)(ed >> 9);
  }
}

// ---------------- L1 fused: gather x(f32) -> reduce -> @W1+b1 -> z(bf16) ----------------

__global__ void k_l1(const float* __restrict__ x, const int* __restrict__ rowoff,
                     const int* __restrict__ col, const float* __restrict__ dis,
                     const float* __restrict__ W, const float* __restrict__ b,
                     u16* __restrict__ z, int n) {
  int wid = (blockIdx.x * blockDim.x + threadIdx.x) >> 6;
  int lane = threadIdx.x & 63;
  if (wid >= n) return;
  float a0 = 0.f, a1 = 0.f, a2 = 0.f;
  int beg = rowoff[wid], end = rowoff[wid + 1];
  for (int e = beg + lane; e < end; e += 64) {
    int j = col[e];
    float dj = dis[j];
    a0 += dj * x[j * 3 + 0];
    a1 += dj * x[j * 3 + 1];
    a2 += dj * x[j * 3 + 2];
  }
#pragma unroll
  for (int off = 32; off; off >>= 1) {
    a0 += __shfl_xor(a0, off); a1 += __shfl_xor(a1, off); a2 += __shfl_xor(a2, off);
  }
  float di = dis[wid];
  a0 = di * (a0 + di * x[wid * 3 + 0]);
  a1 = di * (a1 + di * x[wid * 3 + 1]);
  a2 = di * (a2 + di * x[wid * 3 + 2]);
  float zv = a0 * W[lane] + a1 * W[64 + lane] + a2 * W[128 + lane] + b[lane];
  z[(size_t)wid * 64 + lane] = f2b(zv);
}

// ---------------- aggregations (col-prefetched) ----------------

// D=64: wave/node, 4 sub-waves of 16 lanes (uint2 = 8B each)
__global__ void k_agg64(const u16* __restrict__ u, const int* __restrict__ rowoff,
                        const int* __restrict__ col, const float* __restrict__ dis,
                        u16* __restrict__ a, int n) {
  int wid = (blockIdx.x * blockDim.x + threadIdx.x) >> 6;
  int lane = threadIdx.x & 63;
  if (wid >= n) return;
  int sub = lane >> 4, c = lane & 15;
  const uint2* u2 = (const uint2*)u;
  float acc[4] = {0.f, 0.f, 0.f, 0.f};
  if (sub == 0) {
    float s[4]; unpack4(u2[(size_t)wid * 16 + c], s);
#pragma unroll
    for (int k = 0; k < 4; ++k) acc[k] = s[k];
  }
  int beg = rowoff[wid], end = rowoff[wid + 1];
  int e = beg + sub;
  int j1 = (e < end) ? col[e] : -1;
  int j2 = (e + 4 < end) ? col[e + 4] : -1;
  while (j1 >= 0) {
    int en = e + 8;
    int nj1 = -1, nj2 = -1;
    if (j2 >= 0) {
      if (en < end) nj1 = col[en];
      if (en + 4 < end) nj2 = col[en + 4];
    }
    {
      float f1[4]; unpack4(u2[(size_t)j1 * 16 + c], f1);
#pragma unroll
      for (int k = 0; k < 4; ++k) acc[k] += f1[k];
    }
    if (j2 >= 0) {
      float f2[4]; unpack4(u2[(size_t)j2 * 16 + c], f2);
#pragma unroll
      for (int k = 0; k < 4; ++k) acc[k] += f2[k];
    }
    e = en; j1 = nj1; j2 = nj2;
  }
#pragma unroll
  for (int k = 0; k < 4; ++k) {
    acc[k] += __shfl_xor(acc[k], 16);
    acc[k] += __shfl_xor(acc[k], 32);
  }
  if (sub == 0) {
    float d = dis[wid];
    ((uint2*)a)[(size_t)wid * 16 + c] =
        make_uint2(pack2(d * acc[0], d * acc[1]), pack2(d * acc[2], d * acc[3]));
  }
}

// D=256: wave/node, 2 sub-waves of 32 lanes (uint4 = 16B each)
__global__ void k_agg256(const u16* __restrict__ u, const int* __restrict__ rowoff,
                         const int* __restrict__ col, const float* __restrict__ dis,
                         u16* __restrict__ a, int n) {
  int wid = (blockIdx.x * blockDim.x + threadIdx.x) >> 6;
  int lane = threadIdx.x & 63;
  if (wid >= n) return;
  int sub = lane >> 5, c = lane & 31;
  const uint4* u4 = (const uint4*)u;
  float acc[8] = {0.f, 0.f, 0.f, 0.f, 0.f, 0.f, 0.f, 0.f};
  if (sub == 0) {
    float s[8]; unpack8(u4[(size_t)wid * 32 + c], s);
#pragma unroll
    for (int k = 0; k < 8; ++k) acc[k] = s[k];
  }
  int beg = rowoff[wid], end = rowoff[wid + 1];
  int e = beg + sub;
  int j1 = (e < end) ? col[e] : -1;
  int j2 = (e + 2 < end) ? col[e + 2] : -1;
  while (j1 >= 0) {
    int en = e + 4;
    int nj1 = -1, nj2 = -1;
    if (j2 >= 0) {
      if (en < end) nj1 = col[en];
      if (en + 2 < end) nj2 = col[en + 2];
    }
    {
      float f1[8]; unpack8(u4[(size_t)j1 * 32 + c], f1);
#pragma unroll
      for (int k = 0; k < 8; ++k) acc[k] += f1[k];
    }
    if (j2 >= 0) {
      float f2[8]; unpack8(u4[(size_t)j2 * 32 + c], f2);
#pragma unroll
      for (int k = 0; k < 8; ++k) acc[k] += f2[k];
    }
    e = en; j1 = nj1; j2 = nj2;
  }
#pragma unroll
  for (int k = 0; k < 8; ++k) acc[k] += __shfl_xor(acc[k], 32);
  if (sub == 0) {
    float d = dis[wid];
    uint4 r;
    r.x = pack2(d * acc[0], d * acc[1]);
    r.y = pack2(d * acc[2], d * acc[3]);
    r.z = pack2(d * acc[4], d * acc[5]);
    r.w = pack2(d * acc[6], d * acc[7]);
    ((uint4*)a)[(size_t)wid * 32 + c] = r;
  }
}

// ---------------- BN fold (in-place) ----------------

__global__ void k_u(u16* __restrict__ z, const float* __restrict__ scaleF,
                    const float* __restrict__ shiftF, const float* __restrict__ dis,
                    int n, int lg) {
  size_t idx = (size_t)blockIdx.x * blockDim.x + threadIdx.x;
  size_t tot = ((size_t)n) << lg;
  if (idx >= tot) return;
  int g = (int)(idx & ((1u << lg) - 1));
  int node = (int)(idx >> lg);
  uint4 v = ((const uint4*)z)[idx];
  float f[8];
  unpack8(v, f);
  int f0 = g * 8;
  float4 s0 = *(const float4*)&scaleF[f0];
  float4 s1 = *(const float4*)&scaleF[f0 + 4];
  float4 h0 = *(const float4*)&shiftF[f0];
  float4 h1 = *(const float4*)&shiftF[f0 + 4];
  float d = dis[node];
  float o[8];
  o[0] = f[0] * s0.x + h0.x; o[1] = f[1] * s0.y + h0.y;
  o[2] = f[2] * s0.z + h0.z; o[3] = f[3] * s0.w + h0.w;
  o[4] = f[4] * s1.x + h1.x; o[5] = f[5] * s1.y + h1.y;
  o[6] = f[6] * s1.z + h1.z; o[7] = f[7] * s1.w + h1.w;
#pragma unroll
  for (int k = 0; k < 8; ++k) {
    float a = o[k];
    a = (a > 0.f) ? a : NEG * a;
    o[k] = d * a;
  }
  uint4 r;
  r.x = pack2(o[0], o[1]); r.y = pack2(o[2], o[3]);
  r.z = pack2(o[4], o[5]); r.w = pack2(o[6], o[7]);
  ((uint4*)z)[idx] = r;
}

// ---------------- weight transpose (all 4 MFMA layers at once) ----------------

__global__ void k_wt_all(const float* __restrict__ W2, const float* __restrict__ W3,
                         const float* __restrict__ W4, const float* __restrict__ W5,
                         u16* __restrict__ WT) {
  int i = blockIdx.x * blockDim.x + threadIdx.x;
  const float* W; int K, Fo, base;
  if (i < 4096)        { W = W2; K = 64;  Fo = 64;  base = 0; }
  else if (i < 20480)  { W = W3; K = 64;  Fo = 256; base = 4096; }
  else if (i < 86016)  { W = W4; K = 256; Fo = 256; base = 20480; }
  else if (i < 217088) { W = W5; K = 256; Fo = 512; base = 86016; }
  else return;
  int idx = i - base;
  int f = idx / K, k = idx - f * K;
  WT[i] = f2b(W[(size_t)k * Fo + f]);
}

// ---------------- MFMA GEMM with fused column stats ----------------

// C[n,Fo](bf16) = A[n,K](bf16) @ WT[Fo,K]^T + bias ; psum/psq[col][bx] (LDP)
__global__ __launch_bounds__(256) void k_gemm(const u16* __restrict__ A,
                                              const u16* __restrict__ WT,
                                              const float* __restrict__ bias,
                                              u16* __restrict__ C,
                                              float* __restrict__ psum,
                                              float* __restrict__ psq,
                                              int n, int K, int Fo, int nby) {
  __shared__ u16 As[128][72];
  __shared__ u16 Bs[128][72];
  int tid = threadIdx.x;
  int nwg = gridDim.x;
  int bid = blockIdx.x;
  int q = nwg >> 3, rr = nwg & 7;
  int xcd = bid & 7, pos = bid >> 3;
  int wgid = (xcd < rr ? xcd * (q + 1) : rr * (q + 1) + (xcd - rr) * q) + pos;
  int bx = wgid / nby, by = wgid - bx * nby;
  int bm0 = bx * 128, bn0 = by * 128;
  int lane = tid & 63, wid = tid >> 6;
  int wm = wid >> 1, wn = wid & 1;
  int lr = tid & 127;
  int lh = (tid >> 7) * 32;
  int fr = lane & 15, fg = lane >> 4;
  f32x4 acc[4][4];
#pragma unroll
  for (int i = 0; i < 4; ++i)
#pragma unroll
    for (int j = 0; j < 4; ++j) acc[i][j] = (f32x4)0.0f;

  for (int kt = 0; kt < K; kt += 64) {
    {
      int row = bm0 + lr;
      uint4 v[4];
#pragma unroll
      for (int i = 0; i < 4; ++i) {
        v[i] = make_uint4(0u, 0u, 0u, 0u);
        if (row < n) v[i] = *(const uint4*)&A[(size_t)row * K + kt + lh + i * 8];
      }
      int fo = bn0 + lr;
      uint4 w[4];
#pragma unroll
      for (int i = 0; i < 4; ++i) {
        w[i] = make_uint4(0u, 0u, 0u, 0u);
        if (fo < Fo) w[i] = *(const uint4*)&WT[(size_t)fo * K + kt + lh + i * 8];
      }
#pragma unroll
      for (int i = 0; i < 4; ++i) *(uint4*)&As[lr][lh + i * 8] = v[i];
#pragma unroll
      for (int i = 0; i < 4; ++i) *(uint4*)&Bs[lr][lh + i * 8] = w[i];
    }
    __syncthreads();
#pragma unroll
    for (int ks = 0; ks < 2; ++ks) {
      int k0 = ks * 32 + fg * 8;
      bf16x8 af[4], bf[4];
#pragma unroll
      for (int mi = 0; mi < 4; ++mi) af[mi] = *(const bf16x8*)&As[wm * 64 + mi * 16 + fr][k0];
#pragma unroll
      for (int ni = 0; ni < 4; ++ni) bf[ni] = *(const bf16x8*)&Bs[wn * 64 + ni * 16 + fr][k0];
#pragma unroll
      for (int mi = 0; mi < 4; ++mi)
#pragma unroll
        for (int ni = 0; ni < 4; ++ni)
          acc[mi][ni] = __builtin_amdgcn_mfma_f32_16x16x32_bf16(af[mi], bf[ni], acc[mi][ni], 0, 0, 0);
    }
    __syncthreads();
  }
  float* s2 = (float*)&As[0][0];
#pragma unroll
  for (int ni = 0; ni < 4; ++ni) {
    int gc = bn0 + wn * 64 + ni * 16 + fr;
    float ps = 0.f, pq = 0.f;
    if (gc < Fo) {
      float bv = bias[gc];
#pragma unroll
      for (int mi = 0; mi < 4; ++mi) {
#pragma unroll
        for (int rg = 0; rg < 4; ++rg) {
          int gr = bm0 + wm * 64 + mi * 16 + fg * 4 + rg;
          if (gr < n) {
            float v = acc[mi][ni][rg] + bv;
            C[(size_t)gr * Fo + gc] = f2b(v);
            ps += v; pq += v * v;
          }
        }
      }
    }
    ps += __shfl_xor(ps, 16); ps += __shfl_xor(ps, 32);
    pq += __shfl_xor(pq, 16); pq += __shfl_xor(pq, 32);
    if (fg == 0 && gc < Fo) {
      int cl = wn * 64 + ni * 16 + fr;
      s2[wm * 128 + cl] = ps;
      s2[256 + wm * 128 + cl] = pq;
    }
  }
  __syncthreads();
  if (tid < 128) {
    int gc = bn0 + tid;
    if (gc < Fo) {
      psum[(size_t)gc * LDP + bx] = s2[tid] + s2[128 + tid];
      psq[(size_t)gc * LDP + bx] = s2[256 + tid] + s2[384 + tid];
    }
  }
}

// ---------------- BN stats ----------------

__global__ void k_colred(const u16* __restrict__ z, int Fo, int n, int rowsPerChunk,
                         float* __restrict__ psum, float* __restrict__ psq) {
  int fl = threadIdx.x & 63;
  int rg = threadIdx.x >> 6;
  int f = blockIdx.y * 64 + fl;
  int r0 = blockIdx.x * rowsPerChunk;
  int r1 = min(n, r0 + rowsPerChunk);
  float s = 0.f, sq = 0.f;
  for (int r = r0 + rg; r < r1; r += 4) {
    float v = b2f(z[(size_t)r * Fo + f]);
    s += v;
    sq += v * v;
  }
  __shared__ float ls[4][64], lq[4][64];
  ls[rg][fl] = s; lq[rg][fl] = sq;
  __syncthreads();
  if (rg == 0) {
    psum[(size_t)f * LDP + blockIdx.x] = ls[0][fl] + ls[1][fl] + ls[2][fl] + ls[3][fl];
    psq[(size_t)f * LDP + blockIdx.x] = lq[0][fl] + lq[1][fl] + lq[2][fl] + lq[3][fl];
  }
}

__global__ void k_bnparams(const float* __restrict__ psum, const float* __restrict__ psq,
                           int Fo, int nChunks, int n,
                           const float* __restrict__ g, const float* __restrict__ bt,
                           float* __restrict__ scaleF, float* __restrict__ shiftF) {
  int f = blockIdx.x * 4 + (threadIdx.x >> 6);
  int lane = threadIdx.x & 63;
  if (f >= Fo) return;
  float s = 0.f, sq = 0.f;
  const float* ps = &psum[(size_t)f * LDP];
  const float* pq = &psq[(size_t)f * LDP];
  for (int c = lane; c < nChunks; c += 64) { s += ps[c]; sq += pq[c]; }
#pragma unroll
  for (int off = 32; off; off >>= 1) {
    s += __shfl_xor(s, off);
    sq += __shfl_xor(sq, off);
  }
  if (lane == 0) {
    float inv = 1.0f / (float)n;
    float mu = s * inv;
    float var = sq * inv - mu * mu;
    float rs = rsqrtf(var + EPS_BN) * g[f];
    scaleF[f] = rs;
    shiftF[f] = bt[f] - mu * rs;
  }
}

// ---------------- final layer ----------------

__global__ void k_dot512(const u16* __restrict__ z, const float* __restrict__ scaleF,
                         const float* __restrict__ shiftF, const float* __restrict__ w6,
                         const float* __restrict__ dis, float* __restrict__ v, int n) {
  __shared__ float ws[512], scs[512], shs[512];
  int tid = threadIdx.x;
  for (int i = tid; i < 512; i += 256) { ws[i] = w6[i]; scs[i] = scaleF[i]; shs[i] = shiftF[i]; }
  __syncthreads();
  int lane = tid % 64, wv = tid / 64;
  int node = blockIdx.x * 4 + wv;
  if (node >= n) return;
  uint4 vz = *(const uint4*)&z[(size_t)node * 512 + lane * 8];
  float f[8];
  unpack8(vz, f);
  int f0 = lane * 8;
  float s = 0.f;
#pragma unroll
  for (int k = 0; k < 8; ++k) {
    float a = f[k] * scs[f0 + k] + shs[f0 + k];
    a = (a > 0.f) ? a : NEG * a;
    s += a * ws[f0 + k];
  }
#pragma unroll
  for (int off = 32; off > 0; off >>= 1) s += __shfl_down(s, off);
  if (lane == 0) v[node] = dis[node] * s;
}

__global__ void k_final(const float* __restrict__ v, const int* __restrict__ rowoff,
                        const int* __restrict__ col, const float* __restrict__ dis,
                        const float* __restrict__ b6, float* __restrict__ out, int n) {
  int wid = (blockIdx.x * blockDim.x + threadIdx.x) >> 6;
  int lane = threadIdx.x & 63;
  if (wid >= n) return;
  float acc = 0.f;
  int beg = rowoff[wid], end = rowoff[wid + 1];
  for (int e = beg + lane; e < end; e += 64) acc += v[col[e]];
#pragma unroll
  for (int off = 32; off; off >>= 1) acc += __shfl_xor(acc, off);
  if (lane == 0) {
    float zz = dis[wid] * (acc + v[wid]) + b6[0];
    out[wid] = 1.0f / (1.0f + expf(-zz));
  }
}

// ---------------- driver ----------------

extern "C" void kernel_launch(void* const* d_in, const int* in_sizes, int n_in,
                              void* d_out, int out_size, void* d_ws, size_t ws_size,
                              hipStream_t stream) {
  const float* x = (const float*)d_in[0];
  const int* ei = (const int*)d_in[1];
  const int N = in_sizes[0] / 3;
  const int E = in_sizes[1] / 2;
  const int* srcIdx = ei;
  const int* dstIdx = ei + E;

  const float* W[6]; const float* b[6];
  for (int i = 0; i < 6; ++i) { W[i] = (const float*)d_in[2 + 2 * i]; b[i] = (const float*)d_in[3 + 2 * i]; }
  const float* g[5]; const float* bt[5];
  for (int i = 0; i < 5; ++i) { g[i] = (const float*)d_in[14 + 2 * i]; bt[i] = (const float*)d_in[15 + 2 * i]; }

  char* wsB = (char*)d_ws;
  size_t off = 0;
  auto alloc = [&](size_t bytes) -> void* {
    void* p = wsB + off;
    off = (off + bytes + 255) & ~(size_t)255;
    return p;
  };

  const int NB = cdiv(N, 512);
  int* rowoff = (int*)alloc((size_t)(N + 1) * 4);
  int* col = (int*)alloc((size_t)E * 4);
  float* dis = (float*)alloc((size_t)N * 4);
  float* vbuf = (float*)alloc((size_t)N * 4);
  float* scaleF = (float*)alloc(512 * 4);
  float* shiftF = (float*)alloc(512 * 4);
  u16* WTb = (u16*)alloc((size_t)217088 * 2);
  int* bucketCnt = (int*)alloc(256 * 4);
  int* bucketOff = (int*)alloc(257 * 4);
  int* bucketCur = (int*)alloc(256 * 4);
  const int nbx = cdiv(N, 128);
  float* psum = (float*)alloc((size_t)512 * LDP * 4);
  float* psq = (float*)alloc((size_t)512 * LDP * 4);
  u16* Zb = (u16*)alloc((size_t)N * 512 * 2);
  u16* Ab = (u16*)alloc((size_t)N * 256 * 2);
  u32* ebuf = (u32*)Ab;   // alias: only used during CSR build

  // WT offsets (elements): W2:0, W3:4096, W4:20480, W5:86016
  const int wtOff[5] = {0, 0, 4096, 20480, 86016};
  k_wt_all<<<cdiv(217088, 256), 256, 0, stream>>>(W[1], W[2], W[3], W[4], WTb);

  // ---- CSR build ----
  const int EB = cdiv(E, 4096);
  k_zero_i32<<<1, 256, 0, stream>>>(bucketCnt, 256);
  k_bcount<<<EB, 256, 0, stream>>>(dstIdx, bucketCnt, E);
  k_bscan<<<1, 256, 0, stream>>>(bucketCnt, bucketOff, bucketCur, NB, E);
  k_bucket<<<EB, 256, 0, stream>>>(srcIdx, dstIdx, bucketOff, bucketCur, ebuf, E);
  k_csr<<<NB, 256, 0, stream>>>(ebuf, bucketOff, rowoff, col, dis, N, E, NB);

  auto gemm = [&](const u16* Ain, int layer, int K, int Fo, u16* Cout) {
    int nby = cdiv(Fo, 128);
    k_gemm<<<nbx * nby, 256, 0, stream>>>(Ain, WTb + wtOff[layer], b[layer], Cout,
                                          psum, psq, N, K, Fo, nby);
    k_bnparams<<<cdiv(Fo, 4), 256, 0, stream>>>(psum, psq, Fo, nbx, N,
                                                g[layer], bt[layer], scaleF, shiftF);
  };

  const int waveGrid = cdiv(N * 64, 256);

  // ---- L1 (fully fused) ----
  k_l1<<<waveGrid, 256, 0, stream>>>(x, rowoff, col, dis, W[0], b[0], Zb, N);
  {
    const int rowsPerChunk = 2048;
    const int nChunks = cdiv(N, rowsPerChunk);
    dim3 grid(nChunks, 1);
    k_colred<<<grid, 256, 0, stream>>>(Zb, 64, N, rowsPerChunk, psum, psq);
    k_bnparams<<<cdiv(64, 4), 256, 0, stream>>>(psum, psq, 64, nChunks, N, g[0], bt[0], scaleF, shiftF);
  }

  // ---- L2 ----
  k_u<<<cdiv(N * 8, 256), 256, 0, stream>>>(Zb, scaleF, shiftF, dis, N, 3);
  k_agg64<<<waveGrid, 256, 0, stream>>>(Zb, rowoff, col, dis, Ab, N);
  gemm(Ab, 1, 64, 64, Zb);

  // ---- L3 ----
  k_u<<<cdiv(N * 8, 256), 256, 0, stream>>>(Zb, scaleF, shiftF, dis, N, 3);
  k_agg64<<<waveGrid, 256, 0, stream>>>(Zb, rowoff, col, dis, Ab, N);
  gemm(Ab, 2, 64, 256, Zb);

  // ---- L4 ----
  k_u<<<cdiv(N * 32, 256), 256, 0, stream>>>(Zb, scaleF, shiftF, dis, N, 5);
  k_agg256<<<waveGrid, 256, 0, stream>>>(Zb, rowoff, col, dis, Ab, N);
  gemm(Ab, 3, 256, 256, Zb);

  // ---- L5 ----
  k_u<<<cdiv(N * 32, 256), 256, 0, stream>>>(Zb, scaleF, shiftF, dis, N, 5);
  k_agg256<<<waveGrid, 256, 0, stream>>>(Zb, rowoff, col, dis, Ab, N);
  gemm(Ab, 4, 256, 512, Zb);

  // ---- L6 ----
  k_dot512<<<cdiv(N, 4), 256, 0, stream>>>(Zb, scaleF, shiftF, W[5], dis, vbuf, N);
  k_final<<<waveGrid, 256, 0, stream>>>(vbuf, rowoff, col, dis, b[5], (float*)d_out, N);
}

// Round 7
// 1205.435 us; speedup vs baseline: 2.2408x; 1.0247x over previous
//
#include <hip/hip_runtime.h>
#include <math.h>

typedef unsigned short u16;
typedef unsigned int u32;
typedef __attribute__((ext_vector_type(8))) short bf16x8;
typedef __attribute__((ext_vector_type(4))) float f32x4;

constexpr float EPS_BN = 1e-5f;
constexpr float NEG = 0.1f;
constexpr int LDP = 800;   // leading dim of psum/psq: [feature][chunk<=LDP]

static inline int cdiv(int a, int b) { return (a + b - 1) / b; }

// ---------------- bf16 helpers ----------------

__device__ __forceinline__ float b2f_lo(u32 v) { return __uint_as_float(v << 16); }
__device__ __forceinline__ float b2f_hi(u32 v) { return __uint_as_float(v & 0xFFFF0000u); }
__device__ __forceinline__ float b2f(u16 v) { return __uint_as_float(((u32)v) << 16); }
__device__ __forceinline__ u16 f2b(float f) {
  u32 u = __float_as_uint(f);
  u32 r = u + 0x7FFFu + ((u >> 16) & 1u);
  return (u16)(r >> 16);
}
__device__ __forceinline__ u32 pack2(float a, float b) {
  return (u32)f2b(a) | ((u32)f2b(b) << 16);
}
__device__ __forceinline__ void unpack8(uint4 v, float* o) {
  o[0] = b2f_lo(v.x); o[1] = b2f_hi(v.x);
  o[2] = b2f_lo(v.y); o[3] = b2f_hi(v.y);
  o[4] = b2f_lo(v.z); o[5] = b2f_hi(v.z);
  o[6] = b2f_lo(v.w); o[7] = b2f_hi(v.w);
}
__device__ __forceinline__ void unpack4(uint2 v, float* o) {
  o[0] = b2f_lo(v.x); o[1] = b2f_hi(v.x);
  o[2] = b2f_lo(v.y); o[3] = b2f_hi(v.y);
}
__device__ __forceinline__ float lrelu_s(float t) { return fmaxf(t, NEG * t); }

__device__ __forceinline__ void gload16(const void* g, void* l) {
  __builtin_amdgcn_global_load_lds(
      (const __attribute__((address_space(1))) u32*)g,
      (__attribute__((address_space(3))) u32*)l, 16, 0, 0);
}

// ---------------- CSR build (bucketed, packed ebuf) ----------------

__global__ void k_zero_i32(int* p, int n) {
  int i = blockIdx.x * blockDim.x + threadIdx.x;
  if (i < n) p[i] = 0;
}

__global__ __launch_bounds__(256) void k_bcount(const int* __restrict__ dst,
                                                int* __restrict__ bucketCnt, int E) {
  __shared__ int hist[256];
  int tid = threadIdx.x;
  hist[tid] = 0;
  __syncthreads();
  int e0 = blockIdx.x * 4096;
#pragma unroll
  for (int i = 0; i < 16; ++i) {
    int e = e0 + i * 256 + tid;
    if (e < E) atomicAdd(&hist[dst[e] >> 9], 1);
  }
  __syncthreads();
  int h = hist[tid];
  if (h > 0) atomicAdd(&bucketCnt[tid], h);
}

__global__ void k_bscan(const int* __restrict__ bucketCnt, int* __restrict__ bucketOff,
                        int* __restrict__ bucketCur, int NB, int E) {
  __shared__ int s[256];
  int tid = threadIdx.x;
  int v = (tid < NB) ? bucketCnt[tid] : 0;
  s[tid] = v;
  __syncthreads();
  for (int off = 1; off < 256; off <<= 1) {
    int t = (tid >= off) ? s[tid - off] : 0;
    __syncthreads();
    s[tid] += t;
    __syncthreads();
  }
  if (tid < NB) bucketOff[tid] = s[tid] - v;
  if (tid == NB) bucketOff[NB] = E;
  if (tid < NB) bucketCur[tid] = 0;
}

__global__ __launch_bounds__(256) void k_bucket(const int* __restrict__ src,
                                                const int* __restrict__ dst,
                                                const int* __restrict__ bucketOff,
                                                int* __restrict__ bucketCur,
                                                u32* __restrict__ ebuf, int E) {
  __shared__ int hist[256];
  __shared__ int base[256];
  __shared__ int lcur[256];
  int tid = threadIdx.x;
  hist[tid] = 0; lcur[tid] = 0;
  __syncthreads();
  int e0 = blockIdx.x * 4096;
  int ss[16], dd[16];
#pragma unroll
  for (int i = 0; i < 16; ++i) {
    int e = e0 + i * 256 + tid;
    if (e < E) {
      ss[i] = src[e]; dd[i] = dst[e];
      atomicAdd(&hist[dd[i] >> 9], 1);
    } else dd[i] = -1;
  }
  __syncthreads();
  int h = hist[tid];
  if (h > 0) base[tid] = bucketOff[tid] + atomicAdd(&bucketCur[tid], h);
  __syncthreads();
#pragma unroll
  for (int i = 0; i < 16; ++i) {
    if (dd[i] >= 0) {
      int bk = dd[i] >> 9;
      int p = atomicAdd(&lcur[bk], 1);
      ebuf[base[bk] + p] = ((u32)ss[i] << 9) | ((u32)dd[i] & 511u);
    }
  }
}

__global__ __launch_bounds__(256) void k_csr(const u32* __restrict__ ebuf,
                                             const int* __restrict__ bucketOff,
                                             int* __restrict__ rowoff,
                                             int* __restrict__ col,
                                             float* __restrict__ dis,
                                             int N, int E, int NB) {
  __shared__ int hist[512];
  __shared__ int loff[512];
  __shared__ int scan_s[256];
  int b = blockIdx.x;
  int tid = threadIdx.x;
  int ebase = bucketOff[b], eend = bucketOff[b + 1];
  int ecnt = eend - ebase;
  hist[tid] = 0; hist[tid + 256] = 0;
  __syncthreads();
  for (int i = tid; i < ecnt; i += 256)
    atomicAdd(&hist[ebuf[ebase + i] & 511u], 1);
  __syncthreads();
  int h0 = hist[2 * tid], h1 = hist[2 * tid + 1];
  int ts = h0 + h1;
  scan_s[tid] = ts;
  __syncthreads();
  for (int off = 1; off < 256; off <<= 1) {
    int t = (tid >= off) ? scan_s[tid - off] : 0;
    __syncthreads();
    scan_s[tid] += t;
    __syncthreads();
  }
  int excl = scan_s[tid] - ts;
  loff[2 * tid] = excl;
  loff[2 * tid + 1] = excl + h0;
  __syncthreads();
  int gbase = b * 512;
  for (int i = tid; i < 512; i += 256) {
    int node = gbase + i;
    if (node < N) {
      rowoff[node] = ebase + loff[i];
      dis[node] = rsqrtf((float)hist[i] + 1.0f);
    }
  }
  if (b == NB - 1 && tid == 0) rowoff[N] = E;
  __syncthreads();
  for (int i = tid; i < ecnt; i += 256) {
    u32 ed = ebuf[ebase + i];
    int p = atomicAdd(&loff[ed & 511u], 1);
    col[ebase + p] = (int)(ed >> 9);
  }
}

// ---------------- L1 fused: gather x(f32) -> reduce -> @W1+b1 -> z(bf16) ----------------

__global__ void k_l1(const float* __restrict__ x, const int* __restrict__ rowoff,
                     const int* __restrict__ col, const float* __restrict__ dis,
                     const float* __restrict__ W, const float* __restrict__ b,
                     u16* __restrict__ z, int n) {
  int wid = (blockIdx.x * blockDim.x + threadIdx.x) >> 6;
  int lane = threadIdx.x & 63;
  if (wid >= n) return;
  float a0 = 0.f, a1 = 0.f, a2 = 0.f;
  int beg = rowoff[wid], end = rowoff[wid + 1];
  for (int e = beg + lane; e < end; e += 64) {
    int j = col[e];
    float dj = dis[j];
    a0 += dj * x[j * 3 + 0];
    a1 += dj * x[j * 3 + 1];
    a2 += dj * x[j * 3 + 2];
  }
#pragma unroll
  for (int off = 32; off; off >>= 1) {
    a0 += __shfl_xor(a0, off); a1 += __shfl_xor(a1, off); a2 += __shfl_xor(a2, off);
  }
  float di = dis[wid];
  a0 = di * (a0 + di * x[wid * 3 + 0]);
  a1 = di * (a1 + di * x[wid * 3 + 1]);
  a2 = di * (a2 + di * x[wid * 3 + 2]);
  float zv = a0 * W[lane] + a1 * W[64 + lane] + a2 * W[128 + lane] + b[lane];
  z[(size_t)wid * 64 + lane] = f2b(zv);
}

// ---------------- aggregations with fused BN/lrelu/dis (read raw z) ----------------

// D=64: wave/node, 4 sub-waves of 16 lanes (uint2 = 4 feats each)
__global__ void k_agg64(const u16* __restrict__ z, const int* __restrict__ rowoff,
                        const int* __restrict__ col, const float* __restrict__ dis,
                        const float* __restrict__ scaleF, const float* __restrict__ shiftF,
                        u16* __restrict__ a, int n) {
  int wid = (blockIdx.x * blockDim.x + threadIdx.x) >> 6;
  int lane = threadIdx.x & 63;
  if (wid >= n) return;
  int sub = lane >> 4, c = lane & 15;
  const uint2* z2 = (const uint2*)z;
  float sc[4], sh[4];
  {
    float4 s = *(const float4*)&scaleF[c * 4];
    float4 h = *(const float4*)&shiftF[c * 4];
    sc[0] = s.x; sc[1] = s.y; sc[2] = s.z; sc[3] = s.w;
    sh[0] = h.x; sh[1] = h.y; sh[2] = h.z; sh[3] = h.w;
  }
  float acc[4] = {0.f, 0.f, 0.f, 0.f};
  int beg = rowoff[wid], end = rowoff[wid + 1];
  int e = beg + sub;
  int j1 = (e < end) ? col[e] : -1;
  int j2 = (e + 4 < end) ? col[e + 4] : -1;
  float d1 = (j1 >= 0) ? dis[j1] : 0.f;
  float d2 = (j2 >= 0) ? dis[j2] : 0.f;
  while (j1 >= 0) {
    int en = e + 8;
    int nj1 = -1, nj2 = -1;
    if (j2 >= 0) {
      if (en < end) nj1 = col[en];
      if (en + 4 < end) nj2 = col[en + 4];
    }
    float nd1 = (nj1 >= 0) ? dis[nj1] : 0.f;
    float nd2 = (nj2 >= 0) ? dis[nj2] : 0.f;
    {
      float f1[4]; unpack4(z2[(size_t)j1 * 16 + c], f1);
#pragma unroll
      for (int k = 0; k < 4; ++k) acc[k] += lrelu_s(d1 * (f1[k] * sc[k] + sh[k]));
    }
    if (j2 >= 0) {
      float f2[4]; unpack4(z2[(size_t)j2 * 16 + c], f2);
#pragma unroll
      for (int k = 0; k < 4; ++k) acc[k] += lrelu_s(d2 * (f2[k] * sc[k] + sh[k]));
    }
    e = en; j1 = nj1; j2 = nj2; d1 = nd1; d2 = nd2;
  }
#pragma unroll
  for (int k = 0; k < 4; ++k) {
    acc[k] += __shfl_xor(acc[k], 16);
    acc[k] += __shfl_xor(acc[k], 32);
  }
  if (sub == 0) {
    float dw = dis[wid];
    float s[4]; unpack4(z2[(size_t)wid * 16 + c], s);
#pragma unroll
    for (int k = 0; k < 4; ++k) acc[k] = dw * (acc[k] + lrelu_s(dw * (s[k] * sc[k] + sh[k])));
    ((uint2*)a)[(size_t)wid * 16 + c] =
        make_uint2(pack2(acc[0], acc[1]), pack2(acc[2], acc[3]));
  }
}

// D=256: wave/node, 2 sub-waves of 32 lanes (uint4 = 8 feats each)
__global__ void k_agg256(const u16* __restrict__ z, const int* __restrict__ rowoff,
                         const int* __restrict__ col, const float* __restrict__ dis,
                         const float* __restrict__ scaleF, const float* __restrict__ shiftF,
                         u16* __restrict__ a, int n) {
  int wid = (blockIdx.x * blockDim.x + threadIdx.x) >> 6;
  int lane = threadIdx.x & 63;
  if (wid >= n) return;
  int sub = lane >> 5, c = lane & 31;
  const uint4* z4 = (const uint4*)z;
  float sc[8], sh[8];
  {
    float4 s0 = *(const float4*)&scaleF[c * 8];
    float4 s1 = *(const float4*)&scaleF[c * 8 + 4];
    float4 h0 = *(const float4*)&shiftF[c * 8];
    float4 h1 = *(const float4*)&shiftF[c * 8 + 4];
    sc[0] = s0.x; sc[1] = s0.y; sc[2] = s0.z; sc[3] = s0.w;
    sc[4] = s1.x; sc[5] = s1.y; sc[6] = s1.z; sc[7] = s1.w;
    sh[0] = h0.x; sh[1] = h0.y; sh[2] = h0.z; sh[3] = h0.w;
    sh[4] = h1.x; sh[5] = h1.y; sh[6] = h1.z; sh[7] = h1.w;
  }
  float acc[8] = {0.f, 0.f, 0.f, 0.f, 0.f, 0.f, 0.f, 0.f};
  int beg = rowoff[wid], end = rowoff[wid + 1];
  int e = beg + sub;
  int j1 = (e < end) ? col[e] : -1;
  int j2 = (e + 2 < end) ? col[e + 2] : -1;
  float d1 = (j1 >= 0) ? dis[j1] : 0.f;
  float d2 = (j2 >= 0) ? dis[j2] : 0.f;
  while (j1 >= 0) {
    int en = e + 4;
    int nj1 = -1, nj2 = -1;
    if (j2 >= 0) {
      if (en < end) nj1 = col[en];
      if (en + 2 < end) nj2 = col[en + 2];
    }
    float nd1 = (nj1 >= 0) ? dis[nj1] : 0.f;
    float nd2 = (nj2 >= 0) ? dis[nj2] : 0.f;
    {
      float f1[8]; unpack8(z4[(size_t)j1 * 32 + c], f1);
#pragma unroll
      for (int k = 0; k < 8; ++k) acc[k] += lrelu_s(d1 * (f1[k] * sc[k] + sh[k]));
    }
    if (j2 >= 0) {
      float f2[8]; unpack8(z4[(size_t)j2 * 32 + c], f2);
#pragma unroll
      for (int k = 0; k < 8; ++k) acc[k] += lrelu_s(d2 * (f2[k] * sc[k] + sh[k]));
    }
    e = en; j1 = nj1; j2 = nj2; d1 = nd1; d2 = nd2;
  }
#pragma unroll
  for (int k = 0; k < 8; ++k) acc[k] += __shfl_xor(acc[k], 32);
  if (sub == 0) {
    float dw = dis[wid];
    float s[8]; unpack8(z4[(size_t)wid * 32 + c], s);
#pragma unroll
    for (int k = 0; k < 8; ++k) acc[k] = dw * (acc[k] + lrelu_s(dw * (s[k] * sc[k] + sh[k])));
    uint4 r;
    r.x = pack2(acc[0], acc[1]);
    r.y = pack2(acc[2], acc[3]);
    r.z = pack2(acc[4], acc[5]);
    r.w = pack2(acc[6], acc[7]);
    ((uint4*)a)[(size_t)wid * 32 + c] = r;
  }
}

// ---------------- weight transpose (all 4 MFMA layers at once) ----------------

__global__ void k_wt_all(const float* __restrict__ W2, const float* __restrict__ W3,
                         const float* __restrict__ W4, const float* __restrict__ W5,
                         u16* __restrict__ WT) {
  int i = blockIdx.x * blockDim.x + threadIdx.x;
  const float* W; int K, Fo, base;
  if (i < 4096)        { W = W2; K = 64;  Fo = 64;  base = 0; }
  else if (i < 20480)  { W = W3; K = 64;  Fo = 256; base = 4096; }
  else if (i < 86016)  { W = W4; K = 256; Fo = 256; base = 20480; }
  else if (i < 217088) { W = W5; K = 256; Fo = 512; base = 86016; }
  else return;
  int idx = i - base;
  int f = idx / K, k = idx - f * K;
  WT[i] = f2b(W[(size_t)k * Fo + f]);
}

// ---------------- MFMA GEMM: global_load_lds + XOR-swizzled LDS, fused stats ----------------

// C[n,Fo](bf16) = A[n,K](bf16) @ WT[Fo,K]^T + bias ; psum/psq[col][bx] (LDP)
// A must have >=128 rows of allocation slack past n (unguarded gload_lds).
__global__ __launch_bounds__(256) void k_gemm(const u16* __restrict__ A,
                                              const u16* __restrict__ WT,
                                              const float* __restrict__ bias,
                                              u16* __restrict__ C,
                                              float* __restrict__ psum,
                                              float* __restrict__ psq,
                                              int n, int K, int Fo, int nby) {
  __shared__ u16 As[128 * 64];   // linear, XOR-swizzled: byte ^= (row&7)<<4
  __shared__ u16 Bs[128 * 64];
  int tid = threadIdx.x;
  int nwg = gridDim.x;
  int bid = blockIdx.x;
  int q = nwg >> 3, rr = nwg & 7;
  int xcd = bid & 7, pos = bid >> 3;
  int wgid = (xcd < rr ? xcd * (q + 1) : rr * (q + 1) + (xcd - rr) * q) + pos;
  int bx = wgid / nby, by = wgid - bx * nby;
  int bm0 = bx * 128, bn0 = by * 128;
  int lane = tid & 63, wv = tid >> 6;
  int wm = wv >> 1, wn = wv & 1;
  int fr = lane & 15, fg = lane >> 4;
  // staging geometry: wave wv, instr i -> rows 8*(4*wv+i)..+8 ; lane l -> row +l/8,
  // slot l%8 ; pre-swizzled global col-block cb = (l%8) ^ (l/8)
  int srow = lane >> 3;                 // 0..7
  int cb = (lane & 7) ^ srow;           // 0..7
  f32x4 acc[4][4];
#pragma unroll
  for (int i = 0; i < 4; ++i)
#pragma unroll
    for (int j = 0; j < 4; ++j) acc[i][j] = (f32x4)0.0f;

  for (int kt = 0; kt < K; kt += 64) {
#pragma unroll
    for (int i = 0; i < 4; ++i) {
      int rb = 8 * (4 * wv + i);
      const u16* ga = &A[(size_t)(bm0 + rb + srow) * K + kt + cb * 8];
      gload16(ga, &As[rb * 64 + lane * 8]);
      const u16* gb = &WT[(size_t)(bn0 + rb + srow) * K + kt + cb * 8];
      gload16(gb, &Bs[rb * 64 + lane * 8]);
    }
    __syncthreads();
#pragma unroll
    for (int ks = 0; ks < 2; ++ks) {
      int k0 = ks * 32 + fg * 8;
      bf16x8 af[4], bf[4];
#pragma unroll
      for (int mi = 0; mi < 4; ++mi) {
        int row = wm * 64 + mi * 16 + fr;
        int byt = (row * 128 + k0 * 2) ^ ((row & 7) << 4);
        af[mi] = *(const bf16x8*)((const char*)As + byt);
      }
#pragma unroll
      for (int ni = 0; ni < 4; ++ni) {
        int row = wn * 64 + ni * 16 + fr;
        int byt = (row * 128 + k0 * 2) ^ ((row & 7) << 4);
        bf[ni] = *(const bf16x8*)((const char*)Bs + byt);
      }
#pragma unroll
      for (int mi = 0; mi < 4; ++mi)
#pragma unroll
        for (int ni = 0; ni < 4; ++ni)
          acc[mi][ni] = __builtin_amdgcn_mfma_f32_16x16x32_bf16(af[mi], bf[ni], acc[mi][ni], 0, 0, 0);
    }
    __syncthreads();
  }
  float* s2 = (float*)&As[0];
#pragma unroll
  for (int ni = 0; ni < 4; ++ni) {
    int gc = bn0 + wn * 64 + ni * 16 + fr;
    float ps = 0.f, pq = 0.f;
    if (gc < Fo) {
      float bv = bias[gc];
#pragma unroll
      for (int mi = 0; mi < 4; ++mi) {
#pragma unroll
        for (int rg = 0; rg < 4; ++rg) {
          int gr = bm0 + wm * 64 + mi * 16 + fg * 4 + rg;
          if (gr < n) {
            float v = acc[mi][ni][rg] + bv;
            C[(size_t)gr * Fo + gc] = f2b(v);
            ps += v; pq += v * v;
          }
        }
      }
    }
    ps += __shfl_xor(ps, 16); ps += __shfl_xor(ps, 32);
    pq += __shfl_xor(pq, 16); pq += __shfl_xor(pq, 32);
    if (fg == 0 && gc < Fo) {
      int cl = wn * 64 + ni * 16 + fr;
      s2[wm * 128 + cl] = ps;
      s2[256 + wm * 128 + cl] = pq;
    }
  }
  __syncthreads();
  if (tid < 128) {
    int gc = bn0 + tid;
    if (gc < Fo) {
      psum[(size_t)gc * LDP + bx] = s2[tid] + s2[128 + tid];
      psq[(size_t)gc * LDP + bx] = s2[256 + tid] + s2[384 + tid];
    }
  }
}

// ---------------- BN stats ----------------

__global__ void k_colred(const u16* __restrict__ z, int Fo, int n, int rowsPerChunk,
                         float* __restrict__ psum, float* __restrict__ psq) {
  int fl = threadIdx.x & 63;
  int rg = threadIdx.x >> 6;
  int f = blockIdx.y * 64 + fl;
  int r0 = blockIdx.x * rowsPerChunk;
  int r1 = min(n, r0 + rowsPerChunk);
  float s = 0.f, sq = 0.f;
  for (int r = r0 + rg; r < r1; r += 4) {
    float v = b2f(z[(size_t)r * Fo + f]);
    s += v;
    sq += v * v;
  }
  __shared__ float ls[4][64], lq[4][64];
  ls[rg][fl] = s; lq[rg][fl] = sq;
  __syncthreads();
  if (rg == 0) {
    psum[(size_t)f * LDP + blockIdx.x] = ls[0][fl] + ls[1][fl] + ls[2][fl] + ls[3][fl];
    psq[(size_t)f * LDP + blockIdx.x] = lq[0][fl] + lq[1][fl] + lq[2][fl] + lq[3][fl];
  }
}

__global__ void k_bnparams(const float* __restrict__ psum, const float* __restrict__ psq,
                           int Fo, int nChunks, int n,
                           const float* __restrict__ g, const float* __restrict__ bt,
                           float* __restrict__ scaleF, float* __restrict__ shiftF) {
  int f = blockIdx.x * 4 + (threadIdx.x >> 6);
  int lane = threadIdx.x & 63;
  if (f >= Fo) return;
  float s = 0.f, sq = 0.f;
  const float* ps = &psum[(size_t)f * LDP];
  const float* pq = &psq[(size_t)f * LDP];
  for (int c = lane; c < nChunks; c += 64) { s += ps[c]; sq += pq[c]; }
#pragma unroll
  for (int off = 32; off; off >>= 1) {
    s += __shfl_xor(s, off);
    sq += __shfl_xor(sq, off);
  }
  if (lane == 0) {
    float inv = 1.0f / (float)n;
    float mu = s * inv;
    float var = sq * inv - mu * mu;
    float rs = rsqrtf(var + EPS_BN) * g[f];
    scaleF[f] = rs;
    shiftF[f] = bt[f] - mu * rs;
  }
}

// ---------------- final layer ----------------

__global__ void k_dot512(const u16* __restrict__ z, const float* __restrict__ scaleF,
                         const float* __restrict__ shiftF, const float* __restrict__ w6,
                         const float* __restrict__ dis, float* __restrict__ v, int n) {
  __shared__ float ws[512], scs[512], shs[512];
  int tid = threadIdx.x;
  for (int i = tid; i < 512; i += 256) { ws[i] = w6[i]; scs[i] = scaleF[i]; shs[i] = shiftF[i]; }
  __syncthreads();
  int lane = tid % 64, wv = tid / 64;
  int node = blockIdx.x * 4 + wv;
  if (node >= n) return;
  uint4 vz = *(const uint4*)&z[(size_t)node * 512 + lane * 8];
  float f[8];
  unpack8(vz, f);
  int f0 = lane * 8;
  float s = 0.f;
#pragma unroll
  for (int k = 0; k < 8; ++k) {
    float a = f[k] * scs[f0 + k] + shs[f0 + k];
    a = (a > 0.f) ? a : NEG * a;
    s += a * ws[f0 + k];
  }
#pragma unroll
  for (int off = 32; off > 0; off >>= 1) s += __shfl_down(s, off);
  if (lane == 0) v[node] = dis[node] * s;
}

__global__ void k_final(const float* __restrict__ v, const int* __restrict__ rowoff,
                        const int* __restrict__ col, const float* __restrict__ dis,
                        const float* __restrict__ b6, float* __restrict__ out, int n) {
  int wid = (blockIdx.x * blockDim.x + threadIdx.x) >> 6;
  int lane = threadIdx.x & 63;
  if (wid >= n) return;
  float acc = 0.f;
  int beg = rowoff[wid], end = rowoff[wid + 1];
  for (int e = beg + lane; e < end; e += 64) acc += v[col[e]];
#pragma unroll
  for (int off = 32; off; off >>= 1) acc += __shfl_xor(acc, off);
  if (lane == 0) {
    float zz = dis[wid] * (acc + v[wid]) + b6[0];
    out[wid] = 1.0f / (1.0f + expf(-zz));
  }
}

// ---------------- driver ----------------

extern "C" void kernel_launch(void* const* d_in, const int* in_sizes, int n_in,
                              void* d_out, int out_size, void* d_ws, size_t ws_size,
                              hipStream_t stream) {
  const float* x = (const float*)d_in[0];
  const int* ei = (const int*)d_in[1];
  const int N = in_sizes[0] / 3;
  const int E = in_sizes[1] / 2;
  const int* srcIdx = ei;
  const int* dstIdx = ei + E;

  const float* W[6]; const float* b[6];
  for (int i = 0; i < 6; ++i) { W[i] = (const float*)d_in[2 + 2 * i]; b[i] = (const float*)d_in[3 + 2 * i]; }
  const float* g[5]; const float* bt[5];
  for (int i = 0; i < 5; ++i) { g[i] = (const float*)d_in[14 + 2 * i]; bt[i] = (const float*)d_in[15 + 2 * i]; }

  char* wsB = (char*)d_ws;
  size_t off = 0;
  auto alloc = [&](size_t bytes) -> void* {
    void* p = wsB + off;
    off = (off + bytes + 255) & ~(size_t)255;
    return p;
  };

  const int NB = cdiv(N, 512);
  int* rowoff = (int*)alloc((size_t)(N + 1) * 4);
  int* col = (int*)alloc((size_t)E * 4);
  float* dis = (float*)alloc((size_t)N * 4);
  float* vbuf = (float*)alloc((size_t)N * 4);
  float* scaleF = (float*)alloc(512 * 4);
  float* shiftF = (float*)alloc(512 * 4);
  u16* WTb = (u16*)alloc((size_t)217088 * 2);
  int* bucketCnt = (int*)alloc(256 * 4);
  int* bucketOff = (int*)alloc(257 * 4);
  int* bucketCur = (int*)alloc(256 * 4);
  const int nbx = cdiv(N, 128);
  float* psum = (float*)alloc((size_t)512 * LDP * 4);
  float* psq = (float*)alloc((size_t)512 * LDP * 4);
  u16* Zb = (u16*)alloc((size_t)N * 512 * 2);
  u16* Ab = (u16*)alloc((size_t)(N + 128) * 256 * 2);  // +128 rows slack for gload_lds
  u32* ebuf = (u32*)Ab;   // alias: only used during CSR build

  // WT offsets (elements): W2:0, W3:4096, W4:20480, W5:86016
  const int wtOff[5] = {0, 0, 4096, 20480, 86016};
  k_wt_all<<<cdiv(217088, 256), 256, 0, stream>>>(W[1], W[2], W[3], W[4], WTb);

  // ---- CSR build ----
  const int EB = cdiv(E, 4096);
  k_zero_i32<<<1, 256, 0, stream>>>(bucketCnt, 256);
  k_bcount<<<EB, 256, 0, stream>>>(dstIdx, bucketCnt, E);
  k_bscan<<<1, 256, 0, stream>>>(bucketCnt, bucketOff, bucketCur, NB, E);
  k_bucket<<<EB, 256, 0, stream>>>(srcIdx, dstIdx, bucketOff, bucketCur, ebuf, E);
  k_csr<<<NB, 256, 0, stream>>>(ebuf, bucketOff, rowoff, col, dis, N, E, NB);

  auto gemm = [&](const u16* Ain, int layer, int K, int Fo, u16* Cout) {
    int nby = cdiv(Fo, 128);
    k_gemm<<<nbx * nby, 256, 0, stream>>>(Ain, WTb + wtOff[layer], b[layer], Cout,
                                          psum, psq, N, K, Fo, nby);
    k_bnparams<<<cdiv(Fo, 4), 256, 0, stream>>>(psum, psq, Fo, nbx, N,
                                                g[layer], bt[layer], scaleF, shiftF);
  };

  const int waveGrid = cdiv(N * 64, 256);

  // ---- L1 (fully fused) ----
  k_l1<<<waveGrid, 256, 0, stream>>>(x, rowoff, col, dis, W[0], b[0], Zb, N);
  {
    const int rowsPerChunk = 2048;
    const int nChunks = cdiv(N, rowsPerChunk);
    dim3 grid(nChunks, 1);
    k_colred<<<grid, 256, 0, stream>>>(Zb, 64, N, rowsPerChunk, psum, psq);
    k_bnparams<<<cdiv(64, 4), 256, 0, stream>>>(psum, psq, 64, nChunks, N, g[0], bt[0], scaleF, shiftF);
  }

  // ---- L2 (agg reads raw z + BN params) ----
  k_agg64<<<waveGrid, 256, 0, stream>>>(Zb, rowoff, col, dis, scaleF, shiftF, Ab, N);
  gemm(Ab, 1, 64, 64, Zb);

  // ---- L3 ----
  k_agg64<<<waveGrid, 256, 0, stream>>>(Zb, rowoff, col, dis, scaleF, shiftF, Ab, N);
  gemm(Ab, 2, 64, 256, Zb);

  // ---- L4 ----
  k_agg256<<<waveGrid, 256, 0, stream>>>(Zb, rowoff, col, dis, scaleF, shiftF, Ab, N);
  gemm(Ab, 3, 256, 256, Zb);

  // ---- L5 ----
  k_agg256<<<waveGrid, 256, 0, stream>>>(Zb, rowoff, col, dis, scaleF, shiftF, Ab, N);
  gemm(Ab, 4, 256, 512, Zb);

  // ---- L6 ----
  k_dot512<<<cdiv(N, 4), 256, 0, stream>>>(Zb, scaleF, shiftF, W[5], dis, vbuf, N);
  k_final<<<waveGrid, 256, 0, stream>>>(vbuf, rowoff, col, dis, b[5], (float*)d_out, N);
}

// Round 9
// 1153.990 us; speedup vs baseline: 2.3407x; 1.0446x over previous
//
#include <hip/hip_runtime.h>
#include <math.h>

typedef unsigned short u16;
typedef unsigned int u32;
typedef __attribute__((ext_vector_type(8))) short bf16x8;
typedef __attribute__((ext_vector_type(4))) float f32x4;
typedef __attribute__((ext_vector_type(2))) float f32x2;

constexpr float EPS_BN = 1e-5f;
constexpr float NEG = 0.1f;
constexpr int LDP = 800;   // leading dim of psum/psq: [feature][chunk<=LDP]

static inline int cdiv(int a, int b) { return (a + b - 1) / b; }

// ---------------- bf16 helpers ----------------

__device__ __forceinline__ float b2f_lo(u32 v) { return __uint_as_float(v << 16); }
__device__ __forceinline__ float b2f_hi(u32 v) { return __uint_as_float(v & 0xFFFF0000u); }
__device__ __forceinline__ float b2f(u16 v) { return __uint_as_float(((u32)v) << 16); }
__device__ __forceinline__ u16 f2b(float f) {
  u32 u = __float_as_uint(f);
  u32 r = u + 0x7FFFu + ((u >> 16) & 1u);
  return (u16)(r >> 16);
}
__device__ __forceinline__ u32 pack2(float a, float b) {
  return (u32)f2b(a) | ((u32)f2b(b) << 16);
}
__device__ __forceinline__ void unpack8(uint4 v, float* o) {
  o[0] = b2f_lo(v.x); o[1] = b2f_hi(v.x);
  o[2] = b2f_lo(v.y); o[3] = b2f_hi(v.y);
  o[4] = b2f_lo(v.z); o[5] = b2f_hi(v.z);
  o[6] = b2f_lo(v.w); o[7] = b2f_hi(v.w);
}

__device__ __forceinline__ void gload16(const void* g, void* l) {
  __builtin_amdgcn_global_load_lds(
      (const __attribute__((address_space(1))) u32*)g,
      (__attribute__((address_space(3))) u32*)l, 16, 0, 0);
}

// packed BN+lrelu+accumulate: acc[p] += d * lrelu(z*sc+sh), 8 feats (4 pairs)
__device__ __forceinline__ void bn8_acc(uint4 v, const f32x2* sc2, const f32x2* sh2,
                                        float d, f32x2* acc) {
  const f32x2 dd = {d, d};
  const f32x2 c01 = {NEG, NEG};
  const u32* w = &v.x;
#pragma unroll
  for (int p = 0; p < 4; ++p) {
    f32x2 z = {b2f_lo(w[p]), b2f_hi(w[p])};
    f32x2 t = z * sc2[p] + sh2[p];                       // v_pk_fma
    f32x2 q = __builtin_elementwise_max(t, t * c01);     // v_pk_mul + v_pk_max
    acc[p] = dd * q + acc[p];                            // v_pk_fma
  }
}

// ---------------- CSR build (bucketed, packed ebuf) ----------------

__global__ void k_zero_i32(int* p, int n) {
  int i = blockIdx.x * blockDim.x + threadIdx.x;
  if (i < n) p[i] = 0;
}

__global__ __launch_bounds__(256) void k_bcount(const int* __restrict__ dst,
                                                int* __restrict__ bucketCnt, int E) {
  __shared__ int hist[256];
  int tid = threadIdx.x;
  hist[tid] = 0;
  __syncthreads();
  int e0 = blockIdx.x * 4096;
#pragma unroll
  for (int i = 0; i < 16; ++i) {
    int e = e0 + i * 256 + tid;
    if (e < E) atomicAdd(&hist[dst[e] >> 9], 1);
  }
  __syncthreads();
  int h = hist[tid];
  if (h > 0) atomicAdd(&bucketCnt[tid], h);
}

__global__ void k_bscan(const int* __restrict__ bucketCnt, int* __restrict__ bucketOff,
                        int* __restrict__ bucketCur, int NB, int E) {
  __shared__ int s[256];
  int tid = threadIdx.x;
  int v = (tid < NB) ? bucketCnt[tid] : 0;
  s[tid] = v;
  __syncthreads();
  for (int off = 1; off < 256; off <<= 1) {
    int t = (tid >= off) ? s[tid - off] : 0;
    __syncthreads();
    s[tid] += t;
    __syncthreads();
  }
  if (tid < NB) bucketOff[tid] = s[tid] - v;
  if (tid == NB) bucketOff[NB] = E;
  if (tid < NB) bucketCur[tid] = 0;
}

__global__ __launch_bounds__(256) void k_bucket(const int* __restrict__ src,
                                                const int* __restrict__ dst,
                                                const int* __restrict__ bucketOff,
                                                int* __restrict__ bucketCur,
                                                u32* __restrict__ ebuf, int E) {
  __shared__ int hist[256];
  __shared__ int base[256];
  __shared__ int lcur[256];
  int tid = threadIdx.x;
  hist[tid] = 0; lcur[tid] = 0;
  __syncthreads();
  int e0 = blockIdx.x * 4096;
  int ss[16], dd[16];
#pragma unroll
  for (int i = 0; i < 16; ++i) {
    int e = e0 + i * 256 + tid;
    if (e < E) {
      ss[i] = src[e]; dd[i] = dst[e];
      atomicAdd(&hist[dd[i] >> 9], 1);
    } else dd[i] = -1;
  }
  __syncthreads();
  int h = hist[tid];
  if (h > 0) base[tid] = bucketOff[tid] + atomicAdd(&bucketCur[tid], h);
  __syncthreads();
#pragma unroll
  for (int i = 0; i < 16; ++i) {
    if (dd[i] >= 0) {
      int bk = dd[i] >> 9;
      int p = atomicAdd(&lcur[bk], 1);
      ebuf[base[bk] + p] = ((u32)ss[i] << 9) | ((u32)dd[i] & 511u);
    }
  }
}

__global__ __launch_bounds__(256) void k_csr(const u32* __restrict__ ebuf,
                                             const int* __restrict__ bucketOff,
                                             int* __restrict__ rowoff,
                                             int* __restrict__ col,
                                             float* __restrict__ dis,
                                             int N, int E, int NB) {
  __shared__ int hist[512];
  __shared__ int loff[512];
  __shared__ int scan_s[256];
  int b = blockIdx.x;
  int tid = threadIdx.x;
  int ebase = bucketOff[b], eend = bucketOff[b + 1];
  int ecnt = eend - ebase;
  hist[tid] = 0; hist[tid + 256] = 0;
  __syncthreads();
  for (int i = tid; i < ecnt; i += 256)
    atomicAdd(&hist[ebuf[ebase + i] & 511u], 1);
  __syncthreads();
  int h0 = hist[2 * tid], h1 = hist[2 * tid + 1];
  int ts = h0 + h1;
  scan_s[tid] = ts;
  __syncthreads();
  for (int off = 1; off < 256; off <<= 1) {
    int t = (tid >= off) ? scan_s[tid - off] : 0;
    __syncthreads();
    scan_s[tid] += t;
    __syncthreads();
  }
  int excl = scan_s[tid] - ts;
  loff[2 * tid] = excl;
  loff[2 * tid + 1] = excl + h0;
  __syncthreads();
  int gbase = b * 512;
  for (int i = tid; i < 512; i += 256) {
    int node = gbase + i;
    if (node < N) {
      rowoff[node] = ebase + loff[i];
      dis[node] = rsqrtf((float)hist[i] + 1.0f);
    }
  }
  if (b == NB - 1 && tid == 0) rowoff[N] = E;
  __syncthreads();
  for (int i = tid; i < ecnt; i += 256) {
    u32 ed = ebuf[ebase + i];
    int p = atomicAdd(&loff[ed & 511u], 1);
    col[ebase + p] = (int)(ed >> 9);
  }
}

// ---------------- L1: xd precompute + fused gather/gemm1 ----------------

__global__ void k_xd(const float* __restrict__ x, const float* __restrict__ dis,
                     float4* __restrict__ xd, int n) {
  int i = blockIdx.x * blockDim.x + threadIdx.x;
  if (i >= n) return;
  float d = dis[i];
  xd[i] = make_float4(d * x[i * 3 + 0], d * x[i * 3 + 1], d * x[i * 3 + 2], 0.f);
}

__global__ void k_l1(const float4* __restrict__ xd, const int* __restrict__ rowoff,
                     const int* __restrict__ col, const float* __restrict__ dis,
                     const float* __restrict__ W, const float* __restrict__ b,
                     u16* __restrict__ z, int n) {
  int wid = (blockIdx.x * blockDim.x + threadIdx.x) >> 6;
  int lane = threadIdx.x & 63;
  if (wid >= n) return;
  float a0 = 0.f, a1 = 0.f, a2 = 0.f;
  int beg = rowoff[wid], end = rowoff[wid + 1];
  for (int e = beg + lane; e < end; e += 64) {
    float4 v = xd[col[e]];
    a0 += v.x; a1 += v.y; a2 += v.z;
  }
#pragma unroll
  for (int off = 32; off; off >>= 1) {
    a0 += __shfl_xor(a0, off); a1 += __shfl_xor(a1, off); a2 += __shfl_xor(a2, off);
  }
  float di = dis[wid];
  float4 sv = xd[wid];   // = di * x[wid] : this IS the self term u_i
  a0 = di * (a0 + sv.x);
  a1 = di * (a1 + sv.y);
  a2 = di * (a2 + sv.z);
  float zv = a0 * W[lane] + a1 * W[64 + lane] + a2 * W[128 + lane] + b[lane];
  z[(size_t)wid * 64 + lane] = f2b(zv);
}

// ---------------- aggregations with fused BN/lrelu/dis (packed math) ----------------

// D=64: wave/node, 8 sub-waves of 8 lanes (uint4 = 8 feats each), 16 edges in flight
__global__ void k_agg64(const u16* __restrict__ z, const int* __restrict__ rowoff,
                        const int* __restrict__ col, const float* __restrict__ dis,
                        const float* __restrict__ scaleF, const float* __restrict__ shiftF,
                        u16* __restrict__ a, int n) {
  int wid = (blockIdx.x * blockDim.x + threadIdx.x) >> 6;
  int lane = threadIdx.x & 63;
  if (wid >= n) return;
  int sub = lane >> 3, c = lane & 7;
  const uint4* z4 = (const uint4*)z;
  f32x2 sc2[4], sh2[4];
#pragma unroll
  for (int p = 0; p < 4; ++p) {
    sc2[p] = *(const f32x2*)&scaleF[c * 8 + p * 2];
    sh2[p] = *(const f32x2*)&shiftF[c * 8 + p * 2];
  }
  f32x2 acc[4] = {{0.f, 0.f}, {0.f, 0.f}, {0.f, 0.f}, {0.f, 0.f}};
  int beg = rowoff[wid], end = rowoff[wid + 1];
  int e = beg + sub;
  int j1 = (e < end) ? col[e] : -1;
  int j2 = (e + 8 < end) ? col[e + 8] : -1;
  float d1 = (j1 >= 0) ? dis[j1] : 0.f;
  float d2 = (j2 >= 0) ? dis[j2] : 0.f;
  while (j1 >= 0) {
    int en = e + 16;
    int nj1 = -1, nj2 = -1;
    if (j2 >= 0) {
      if (en < end) nj1 = col[en];
      if (en + 8 < end) nj2 = col[en + 8];
    }
    float nd1 = (nj1 >= 0) ? dis[nj1] : 0.f;
    float nd2 = (nj2 >= 0) ? dis[nj2] : 0.f;
    bn8_acc(z4[(size_t)j1 * 8 + c], sc2, sh2, d1, acc);
    if (j2 >= 0) bn8_acc(z4[(size_t)j2 * 8 + c], sc2, sh2, d2, acc);
    e = en; j1 = nj1; j2 = nj2; d1 = nd1; d2 = nd2;
  }
  float* af = (float*)acc;
#pragma unroll
  for (int k = 0; k < 8; ++k) {
    af[k] += __shfl_xor(af[k], 8);
    af[k] += __shfl_xor(af[k], 16);
    af[k] += __shfl_xor(af[k], 32);
  }
  if (sub == 0) {
    float dw = dis[wid];
    bn8_acc(z4[(size_t)wid * 8 + c], sc2, sh2, dw, acc);
    uint4 r;
    r.x = pack2(dw * af[0], dw * af[1]);
    r.y = pack2(dw * af[2], dw * af[3]);
    r.z = pack2(dw * af[4], dw * af[5]);
    r.w = pack2(dw * af[6], dw * af[7]);
    ((uint4*)a)[(size_t)wid * 8 + c] = r;
  }
}

// D=256: wave/node, 2 sub-waves of 32 lanes (uint4 = 8 feats each)
__global__ void k_agg256(const u16* __restrict__ z, const int* __restrict__ rowoff,
                         const int* __restrict__ col, const float* __restrict__ dis,
                         const float* __restrict__ scaleF, const float* __restrict__ shiftF,
                         u16* __restrict__ a, int n) {
  int wid = (blockIdx.x * blockDim.x + threadIdx.x) >> 6;
  int lane = threadIdx.x & 63;
  if (wid >= n) return;
  int sub = lane >> 5, c = lane & 31;
  const uint4* z4 = (const uint4*)z;
  f32x2 sc2[4], sh2[4];
#pragma unroll
  for (int p = 0; p < 4; ++p) {
    sc2[p] = *(const f32x2*)&scaleF[c * 8 + p * 2];
    sh2[p] = *(const f32x2*)&shiftF[c * 8 + p * 2];
  }
  f32x2 acc[4] = {{0.f, 0.f}, {0.f, 0.f}, {0.f, 0.f}, {0.f, 0.f}};
  int beg = rowoff[wid], end = rowoff[wid + 1];
  int e = beg + sub;
  int j1 = (e < end) ? col[e] : -1;
  int j2 = (e + 2 < end) ? col[e + 2] : -1;
  float d1 = (j1 >= 0) ? dis[j1] : 0.f;
  float d2 = (j2 >= 0) ? dis[j2] : 0.f;
  while (j1 >= 0) {
    int en = e + 4;
    int nj1 = -1, nj2 = -1;
    if (j2 >= 0) {
      if (en < end) nj1 = col[en];
      if (en + 2 < end) nj2 = col[en + 2];
    }
    float nd1 = (nj1 >= 0) ? dis[nj1] : 0.f;
    float nd2 = (nj2 >= 0) ? dis[nj2] : 0.f;
    bn8_acc(z4[(size_t)j1 * 32 + c], sc2, sh2, d1, acc);
    if (j2 >= 0) bn8_acc(z4[(size_t)j2 * 32 + c], sc2, sh2, d2, acc);
    e = en; j1 = nj1; j2 = nj2; d1 = nd1; d2 = nd2;
  }
  float* af = (float*)acc;
#pragma unroll
  for (int k = 0; k < 8; ++k) af[k] += __shfl_xor(af[k], 32);
  if (sub == 0) {
    float dw = dis[wid];
    bn8_acc(z4[(size_t)wid * 32 + c], sc2, sh2, dw, acc);
    uint4 r;
    r.x = pack2(dw * af[0], dw * af[1]);
    r.y = pack2(dw * af[2], dw * af[3]);
    r.z = pack2(dw * af[4], dw * af[5]);
    r.w = pack2(dw * af[6], dw * af[7]);
    ((uint4*)a)[(size_t)wid * 32 + c] = r;
  }
}

// ---------------- weight transpose (all 4 MFMA layers at once) ----------------

__global__ void k_wt_all(const float* __restrict__ W2, const float* __restrict__ W3,
                         const float* __restrict__ W4, const float* __restrict__ W5,
                         u16* __restrict__ WT) {
  int i = blockIdx.x * blockDim.x + threadIdx.x;
  const float* W; int K, Fo, base;
  if (i < 4096)        { W = W2; K = 64;  Fo = 64;  base = 0; }
  else if (i < 20480)  { W = W3; K = 64;  Fo = 256; base = 4096; }
  else if (i < 86016)  { W = W4; K = 256; Fo = 256; base = 20480; }
  else if (i < 217088) { W = W5; K = 256; Fo = 512; base = 86016; }
  else return;
  int idx = i - base;
  int f = idx / K, k = idx - f * K;
  WT[i] = f2b(W[(size_t)k * Fo + f]);
}

// ---------------- MFMA GEMM: global_load_lds + XOR-swizzled LDS, fused stats ----------------

// C[n,Fo](bf16) = A[n,K](bf16) @ WT[Fo,K]^T + bias ; psum/psq[col][bx] (LDP)
// A must have >=128 rows of allocation slack past n (unguarded gload_lds).
__global__ __launch_bounds__(256) void k_gemm(const u16* __restrict__ A,
                                              const u16* __restrict__ WT,
                                              const float* __restrict__ bias,
                                              u16* __restrict__ C,
                                              float* __restrict__ psum,
                                              float* __restrict__ psq,
                                              int n, int K, int Fo, int nby) {
  __shared__ u16 As[128 * 64];   // linear, XOR-swizzled: byte ^= (row&7)<<4
  __shared__ u16 Bs[128 * 64];
  int tid = threadIdx.x;
  int nwg = gridDim.x;
  int bid = blockIdx.x;
  int q = nwg >> 3, rr = nwg & 7;
  int xcd = bid & 7, pos = bid >> 3;
  int wgid = (xcd < rr ? xcd * (q + 1) : rr * (q + 1) + (xcd - rr) * q) + pos;
  int bx = wgid / nby, by = wgid - bx * nby;
  int bm0 = bx * 128, bn0 = by * 128;
  int lane = tid & 63, wv = tid >> 6;
  int wm = wv >> 1, wn = wv & 1;
  int fr = lane & 15, fg = lane >> 4;
  int srow = lane >> 3;                 // 0..7
  int cb = (lane & 7) ^ srow;           // 0..7
  f32x4 acc[4][4];
#pragma unroll
  for (int i = 0; i < 4; ++i)
#pragma unroll
    for (int j = 0; j < 4; ++j) acc[i][j] = (f32x4)0.0f;

  for (int kt = 0; kt < K; kt += 64) {
#pragma unroll
    for (int i = 0; i < 4; ++i) {
      int rb = 8 * (4 * wv + i);
      const u16* ga = &A[(size_t)(bm0 + rb + srow) * K + kt + cb * 8];
      gload16(ga, &As[rb * 64 + lane * 8]);
      const u16* gb = &WT[(size_t)(bn0 + rb + srow) * K + kt + cb * 8];
      gload16(gb, &Bs[rb * 64 + lane * 8]);
    }
    __syncthreads();
#pragma unroll
    for (int ks = 0; ks < 2; ++ks) {
      int k0 = ks * 32 + fg * 8;
      bf16x8 af[4], bf[4];
#pragma unroll
      for (int mi = 0; mi < 4; ++mi) {
        int row = wm * 64 + mi * 16 + fr;
        int byt = (row * 128 + k0 * 2) ^ ((row & 7) << 4);
        af[mi] = *(const bf16x8*)((const char*)As + byt);
      }
#pragma unroll
      for (int ni = 0; ni < 4; ++ni) {
        int row = wn * 64 + ni * 16 + fr;
        int byt = (row * 128 + k0 * 2) ^ ((row & 7) << 4);
        bf[ni] = *(const bf16x8*)((const char*)Bs + byt);
      }
#pragma unroll
      for (int mi = 0; mi < 4; ++mi)
#pragma unroll
        for (int ni = 0; ni < 4; ++ni)
          acc[mi][ni] = __builtin_amdgcn_mfma_f32_16x16x32_bf16(af[mi], bf[ni], acc[mi][ni], 0, 0, 0);
    }
    __syncthreads();
  }
  float* s2 = (float*)&As[0];
#pragma unroll
  for (int ni = 0; ni < 4; ++ni) {
    int gc = bn0 + wn * 64 + ni * 16 + fr;
    float ps = 0.f, pq = 0.f;
    if (gc < Fo) {
      float bv = bias[gc];
#pragma unroll
      for (int mi = 0; mi < 4; ++mi) {
#pragma unroll
        for (int rg = 0; rg < 4; ++rg) {
          int gr = bm0 + wm * 64 + mi * 16 + fg * 4 + rg;
          if (gr < n) {
            float v = acc[mi][ni][rg] + bv;
            C[(size_t)gr * Fo + gc] = f2b(v);
            ps += v; pq += v * v;
          }
        }
      }
    }
    ps += __shfl_xor(ps, 16); ps += __shfl_xor(ps, 32);
    pq += __shfl_xor(pq, 16); pq += __shfl_xor(pq, 32);
    if (fg == 0 && gc < Fo) {
      int cl = wn * 64 + ni * 16 + fr;
      s2[wm * 128 + cl] = ps;
      s2[256 + wm * 128 + cl] = pq;
    }
  }
  __syncthreads();
  if (tid < 128) {
    int gc = bn0 + tid;
    if (gc < Fo) {
      psum[(size_t)gc * LDP + bx] = s2[tid] + s2[128 + tid];
      psq[(size_t)gc * LDP + bx] = s2[256 + tid] + s2[384 + tid];
    }
  }
}

// ---------------- BN stats ----------------

__global__ void k_colred(const u16* __restrict__ z, int Fo, int n, int rowsPerChunk,
                         float* __restrict__ psum, float* __restrict__ psq) {
  int fl = threadIdx.x & 63;
  int rg = threadIdx.x >> 6;
  int f = blockIdx.y * 64 + fl;
  int r0 = blockIdx.x * rowsPerChunk;
  int r1 = min(n, r0 + rowsPerChunk);
  float s = 0.f, sq = 0.f;
  for (int r = r0 + rg; r < r1; r += 4) {
    float v = b2f(z[(size_t)r * Fo + f]);
    s += v;
    sq += v * v;
  }
  __shared__ float ls[4][64], lq[4][64];
  ls[rg][fl] = s; lq[rg][fl] = sq;
  __syncthreads();
  if (rg == 0) {
    psum[(size_t)f * LDP + blockIdx.x] = ls[0][fl] + ls[1][fl] + ls[2][fl] + ls[3][fl];
    psq[(size_t)f * LDP + blockIdx.x] = lq[0][fl] + lq[1][fl] + lq[2][fl] + lq[3][fl];
  }
}

__global__ void k_bnparams(const float* __restrict__ psum, const float* __restrict__ psq,
                           int Fo, int nChunks, int n,
                           const float* __restrict__ g, const float* __restrict__ bt,
                           float* __restrict__ scaleF, float* __restrict__ shiftF) {
  int f = blockIdx.x * 4 + (threadIdx.x >> 6);
  int lane = threadIdx.x & 63;
  if (f >= Fo) return;
  float s = 0.f, sq = 0.f;
  const float* ps = &psum[(size_t)f * LDP];
  const float* pq = &psq[(size_t)f * LDP];
  for (int c = lane; c < nChunks; c += 64) { s += ps[c]; sq += pq[c]; }
#pragma unroll
  for (int off = 32; off; off >>= 1) {
    s += __shfl_xor(s, off);
    sq += __shfl_xor(sq, off);
  }
  if (lane == 0) {
    float inv = 1.0f / (float)n;
    float mu = s * inv;
    float var = sq * inv - mu * mu;
    float rs = rsqrtf(var + EPS_BN) * g[f];
    scaleF[f] = rs;
    shiftF[f] = bt[f] - mu * rs;
  }
}

// ---------------- final layer ----------------

__global__ void k_dot512(const u16* __restrict__ z, const float* __restrict__ scaleF,
                         const float* __restrict__ shiftF, const float* __restrict__ w6,
                         const float* __restrict__ dis, float* __restrict__ v, int n) {
  __shared__ float ws[512], scs[512], shs[512];
  int tid = threadIdx.x;
  for (int i = tid; i < 512; i += 256) { ws[i] = w6[i]; scs[i] = scaleF[i]; shs[i] = shiftF[i]; }
  __syncthreads();
  int lane = tid % 64, wv = tid / 64;
  int node = blockIdx.x * 4 + wv;
  if (node >= n) return;
  uint4 vz = *(const uint4*)&z[(size_t)node * 512 + lane * 8];
  float f[8];
  unpack8(vz, f);
  int f0 = lane * 8;
  float s = 0.f;
#pragma unroll
  for (int k = 0; k < 8; ++k) {
    float a = f[k] * scs[f0 + k] + shs[f0 + k];
    a = (a > 0.f) ? a : NEG * a;
    s += a * ws[f0 + k];
  }
#pragma unroll
  for (int off = 32; off > 0; off >>= 1) s += __shfl_down(s, off);
  if (lane == 0) v[node] = dis[node] * s;
}

__global__ void k_final(const float* __restrict__ v, const int* __restrict__ rowoff,
                        const int* __restrict__ col, const float* __restrict__ dis,
                        const float* __restrict__ b6, float* __restrict__ out, int n) {
  int wid = (blockIdx.x * blockDim.x + threadIdx.x) >> 6;
  int lane = threadIdx.x & 63;
  if (wid >= n) return;
  float acc = 0.f;
  int beg = rowoff[wid], end = rowoff[wid + 1];
  for (int e = beg + lane; e < end; e += 64) acc += v[col[e]];
#pragma unroll
  for (int off = 32; off; off >>= 1) acc += __shfl_xor(acc, off);
  if (lane == 0) {
    float zz = dis[wid] * (acc + v[wid]) + b6[0];
    out[wid] = 1.0f / (1.0f + expf(-zz));
  }
}

// ---------------- driver ----------------

extern "C" void kernel_launch(void* const* d_in, const int* in_sizes, int n_in,
                              void* d_out, int out_size, void* d_ws, size_t ws_size,
                              hipStream_t stream) {
  const float* x = (const float*)d_in[0];
  const int* ei = (const int*)d_in[1];
  const int N = in_sizes[0] / 3;
  const int E = in_sizes[1] / 2;
  const int* srcIdx = ei;
  const int* dstIdx = ei + E;

  const float* W[6]; const float* b[6];
  for (int i = 0; i < 6; ++i) { W[i] = (const float*)d_in[2 + 2 * i]; b[i] = (const float*)d_in[3 + 2 * i]; }
  const float* g[5]; const float* bt[5];
  for (int i = 0; i < 5; ++i) { g[i] = (const float*)d_in[14 + 2 * i]; bt[i] = (const float*)d_in[15 + 2 * i]; }

  char* wsB = (char*)d_ws;
  size_t off = 0;
  auto alloc = [&](size_t bytes) -> void* {
    void* p = wsB + off;
    off = (off + bytes + 255) & ~(size_t)255;
    return p;
  };

  const int NB = cdiv(N, 512);
  int* rowoff = (int*)alloc((size_t)(N + 1) * 4);
  int* col = (int*)alloc((size_t)E * 4);
  float* dis = (float*)alloc((size_t)N * 4);
  float* vbuf = (float*)alloc((size_t)N * 4);
  float* scaleF = (float*)alloc(512 * 4);
  float* shiftF = (float*)alloc(512 * 4);
  float4* xd = (float4*)alloc((size_t)N * 16);
  u16* WTb = (u16*)alloc((size_t)217088 * 2);
  int* bucketCnt = (int*)alloc(256 * 4);
  int* bucketOff = (int*)alloc(257 * 4);
  int* bucketCur = (int*)alloc(256 * 4);
  const int nbx = cdiv(N, 128);
  float* psum = (float*)alloc((size_t)512 * LDP * 4);
  float* psq = (float*)alloc((size_t)512 * LDP * 4);
  u16* Zb = (u16*)alloc((size_t)N * 512 * 2);
  u16* Ab = (u16*)alloc((size_t)(N + 128) * 256 * 2);  // +128 rows slack for gload_lds
  u32* ebuf = (u32*)Ab;   // alias: only used during CSR build

  // WT offsets (elements): W2:0, W3:4096, W4:20480, W5:86016
  const int wtOff[5] = {0, 0, 4096, 20480, 86016};
  k_wt_all<<<cdiv(217088, 256), 256, 0, stream>>>(W[1], W[2], W[3], W[4], WTb);

  // ---- CSR build ----
  const int EB = cdiv(E, 4096);
  k_zero_i32<<<1, 256, 0, stream>>>(bucketCnt, 256);
  k_bcount<<<EB, 256, 0, stream>>>(dstIdx, bucketCnt, E);
  k_bscan<<<1, 256, 0, stream>>>(bucketCnt, bucketOff, bucketCur, NB, E);
  k_bucket<<<EB, 256, 0, stream>>>(srcIdx, dstIdx, bucketOff, bucketCur, ebuf, E);
  k_csr<<<NB, 256, 0, stream>>>(ebuf, bucketOff, rowoff, col, dis, N, E, NB);

  auto gemm = [&](const u16* Ain, int layer, int K, int Fo, u16* Cout) {
    int nby = cdiv(Fo, 128);
    k_gemm<<<nbx * nby, 256, 0, stream>>>(Ain, WTb + wtOff[layer], b[layer], Cout,
                                          psum, psq, N, K, Fo, nby);
    k_bnparams<<<cdiv(Fo, 4), 256, 0, stream>>>(psum, psq, Fo, nbx, N,
                                                g[layer], bt[layer], scaleF, shiftF);
  };

  const int waveGrid = cdiv(N * 64, 256);

  // ---- L1 (fully fused) ----
  k_xd<<<cdiv(N, 256), 256, 0, stream>>>(x, dis, xd, N);
  k_l1<<<waveGrid, 256, 0, stream>>>(xd, rowoff, col, dis, W[0], b[0], Zb, N);
  {
    const int rowsPerChunk = 2048;
    const int nChunks = cdiv(N, rowsPerChunk);
    dim3 grid(nChunks, 1);
    k_colred<<<grid, 256, 0, stream>>>(Zb, 64, N, rowsPerChunk, psum, psq);
    k_bnparams<<<cdiv(64, 4), 256, 0, stream>>>(psum, psq, 64, nChunks, N, g[0], bt[0], scaleF, shiftF);
  }

  // ---- L2 (agg reads raw z + BN params) ----
  k_agg64<<<waveGrid, 256, 0, stream>>>(Zb, rowoff, col, dis, scaleF, shiftF, Ab, N);
  gemm(Ab, 1, 64, 64, Zb);

  // ---- L3 ----
  k_agg64<<<waveGrid, 256, 0, stream>>>(Zb, rowoff, col, dis, scaleF, shiftF, Ab, N);
  gemm(Ab, 2, 64, 256, Zb);

  // ---- L4 ----
  k_agg256<<<waveGrid, 256, 0, stream>>>(Zb, rowoff, col, dis, scaleF, shiftF, Ab, N);
  gemm(Ab, 3, 256, 256, Zb);

  // ---- L5 ----
  k_agg256<<<waveGrid, 256, 0, stream>>>(Zb, rowoff, col, dis, scaleF, shiftF, Ab, N);
  gemm(Ab, 4, 256, 512, Zb);

  // ---- L6 ----
  k_dot512<<<cdiv(N, 4), 256, 0, stream>>>(Zb, scaleF, shiftF, W[5], dis, vbuf, N);
  k_final<<<waveGrid, 256, 0, stream>>>(vbuf, rowoff, col, dis, b[5], (float*)d_out, N);
}